// Round 1
// baseline (608.469 us; speedup 1.0000x reference)
//
#include <hip/hip_runtime.h>
#include <math.h>

#define NN 4096

// ---------- helpers ----------
static __device__ __forceinline__ unsigned enc_f(float f){
    unsigned u = __float_as_uint(f);
    return (u & 0x80000000u) ? ~u : (u | 0x80000000u);
}
static __device__ __forceinline__ float dec_f(unsigned u){
    unsigned b = (u & 0x80000000u) ? (u & 0x7fffffffu) : ~u;
    return __uint_as_float(b);
}

// ---------- phase 1: x0 assembly + Ot column sums ----------
__global__ void k_prep(const float* __restrict__ dx1, const float* __restrict__ dx2,
                       const float* __restrict__ Wk, const float* __restrict__ bk,
                       float* __restrict__ x0, float* __restrict__ colsum){
    int n = blockIdx.x*blockDim.x + threadIdx.x;
    if (n >= NN) return;
    float wk[8];
    #pragma unroll
    for (int j=0;j<8;j++) wk[j] = Wk[j];
    float bkv = bk[0];
    #pragma unroll
    for (int c=0;c<4;c++) x0[n*8+c] = dx1[n*4+c];
    #pragma unroll
    for (int c=0;c<4;c++){
        float acc = bkv;
        #pragma unroll
        for (int j=0;j<8;j++) acc += dx2[(n*8+j)*4+c]*wk[j];
        x0[n*8+4+c] = acc;
        atomicAdd(&colsum[c], acc);
    }
}

// ---------- phase 2: distances, row max, top-9 knn ----------
__global__ __launch_bounds__(256) void k_dist(const float* __restrict__ dx1,
        float* __restrict__ dist, float* __restrict__ maxd, int* __restrict__ nbr){
    __shared__ float row[NN];
    __shared__ float sd[256];
    __shared__ int   si[256];
    int i = blockIdx.x;
    int tid = threadIdx.x;
    float px = dx1[i*4+0], py = dx1[i*4+1];
    float lmax = 0.f;
    for (int j = tid; j < NN; j += 256){
        float dx = px - dx1[j*4+0];
        float dy = py - dx1[j*4+1];
        float d = sqrtf(dx*dx+dy*dy);
        dist[(size_t)i*NN + j] = d;
        lmax = fmaxf(lmax, d);
        row[j] = (j==i) ? INFINITY : d;
    }
    sd[tid] = lmax; __syncthreads();
    for (int s=128;s>0;s>>=1){ if(tid<s) sd[tid]=fmaxf(sd[tid],sd[tid+s]); __syncthreads(); }
    if (tid==0) maxd[i] = sd[0];
    __syncthreads();
    float lastd = -1.f; int lasti = -1;
    for (int t=0;t<9;t++){
        float md = INFINITY; int mi = NN;
        for (int j = tid; j < NN; j += 256){
            float d = row[j];
            bool ok = (d > lastd) || (d == lastd && j > lasti);
            if (ok && (d < md || (d == md && j < mi))){ md = d; mi = j; }
        }
        sd[tid]=md; si[tid]=mi; __syncthreads();
        for (int s=128;s>0;s>>=1){
            if (tid<s){
                if (sd[tid+s] < sd[tid] || (sd[tid+s]==sd[tid] && si[tid+s]<si[tid])){
                    sd[tid]=sd[tid+s]; si[tid]=si[tid+s];
                }
            }
            __syncthreads();
        }
        lastd = sd[0]; lasti = si[0];
        if (tid==0) nbr[i*9+t] = lasti;
        __syncthreads();
    }
}

// ---------- phase 3: GCN ----------
__global__ void k_deg_init(float* d3, float* d5, float* d9){
    int i = blockIdx.x*blockDim.x + threadIdx.x;
    if (i<NN){ d3[i]=1.f; d5[i]=1.f; d9[i]=1.f; }
}
__global__ void k_deg(const int* __restrict__ nbr, float* __restrict__ deg3,
                      float* __restrict__ deg5, float* __restrict__ deg9){
    int i = blockIdx.x*blockDim.x + threadIdx.x;
    if (i>=NN) return;
    #pragma unroll
    for (int t=0;t<9;t++){
        int j = nbr[i*9+t];
        atomicAdd(&deg9[j], 1.f);
        if (t<5) atomicAdd(&deg5[j], 1.f);
        if (t<3) atomicAdd(&deg3[j], 1.f);
    }
}
__global__ void k_gcn1_xw(const float* __restrict__ x0, const float* __restrict__ Wg1,
                          const float* __restrict__ deg, float* __restrict__ y1){
    int idx = blockIdx.x*blockDim.x + threadIdx.x;
    if (idx >= NN*64) return;
    int n = idx >> 6, c = idx & 63;
    float acc = 0.f;
    #pragma unroll
    for (int k=0;k<8;k++) acc += x0[n*8+k]*Wg1[k*64+c];
    y1[idx] = rsqrtf(deg[n]) * acc;
}
__global__ void k_scat(const int* __restrict__ nbr, const float* __restrict__ y,
                       float* __restrict__ acc, int kk, int csh, int nedge){
    int g = blockIdx.x*blockDim.x + threadIdx.x;
    int e = g >> csh;
    if (e >= nedge) return;
    int c = g & ((1<<csh)-1);
    int i = e / kk, t = e - i*kk;
    int j = nbr[i*9+t];
    atomicAdd(&acc[((size_t)j<<csh)+c], y[((size_t)i<<csh)+c]);
}
__global__ void k_gcn1_fin(const float* __restrict__ y1, const float* __restrict__ acc1,
                           const float* __restrict__ bg1, const float* __restrict__ deg,
                           float* __restrict__ h1){
    int idx = blockIdx.x*blockDim.x + threadIdx.x;
    if (idx >= NN*64) return;
    int n = idx>>6, c = idx&63;
    float v = rsqrtf(deg[n])*(y1[idx]+acc1[idx]) + bg1[c];
    h1[idx] = v > 0.f ? v : 0.f;
}
__global__ void k_gcn2_xw(const float* __restrict__ h1, const float* __restrict__ Wg2,
                          const float* __restrict__ deg, float* __restrict__ y2){
    int idx = blockIdx.x*blockDim.x + threadIdx.x;
    if (idx >= NN*128) return;
    int n = idx>>7, c = idx&127;
    float acc=0.f;
    #pragma unroll 8
    for (int k=0;k<64;k++) acc += h1[n*64+k]*Wg2[k*128+c];
    y2[idx] = rsqrtf(deg[n])*acc;
}
__global__ __launch_bounds__(128) void k_gcn2_fin(const float* __restrict__ y2, const float* __restrict__ acc2,
        const float* __restrict__ bg2, const float* __restrict__ deg,
        float* __restrict__ emb, int off){
    __shared__ float sm[2], ss[2];
    int n = blockIdx.x, c = threadIdx.x;
    int idx = n*128+c;
    float v = rsqrtf(deg[n])*(y2[idx]+acc2[idx]) + bg2[c];
    float m = v;
    #pragma unroll
    for (int s=1;s<64;s<<=1) m = fmaxf(m, __shfl_xor(m, s, 64));
    if ((c&63)==0) sm[c>>6] = m;
    __syncthreads();
    m = fmaxf(sm[0], sm[1]);
    float e = expf(v - m);
    float t = e;
    #pragma unroll
    for (int s=1;s<64;s<<=1) t += __shfl_xor(t, s, 64);
    if ((c&63)==0) ss[c>>6] = t;
    __syncthreads();
    t = ss[0]+ss[1];
    emb[n*384 + off + c] = v - m - logf(t);
}

// ---------- phase 4: q/k projections ----------
__global__ __launch_bounds__(256) void k_qk(const float* __restrict__ emb,
        const float* __restrict__ Wq, const float* __restrict__ bq,
        const float* __restrict__ Wkey, const float* __restrict__ bkey,
        float* __restrict__ q, float* __restrict__ kbuf){
    __shared__ float es[8][384];
    int n0 = blockIdx.x*8;
    int tid = threadIdx.x;
    for (int idx=tid; idx<8*384; idx+=256){
        int m = idx/384, k = idx%384;
        es[m][k] = emb[(n0+m)*384+k];
    }
    __syncthreads();
    int c = tid & 127;
    int sel = tid >> 7;
    const float* W = sel ? Wkey : Wq;
    float b = sel ? bkey[c] : bq[c];
    float acc[8];
    #pragma unroll
    for (int m=0;m<8;m++) acc[m]=b;
    for (int k=0;k<384;k++){
        float w = W[k*128+c];
        #pragma unroll
        for (int m=0;m<8;m++) acc[m] += es[m][k]*w;
    }
    float* out = sel ? kbuf : q;
    #pragma unroll
    for (int m=0;m<8;m++) out[(n0+m)*128+c] = acc[m];
}

// ---------- phase 5: scores = q @ k^T (unscaled; scaling cancels in A) ----------
__global__ __launch_bounds__(256) void k_scores(const float* __restrict__ q,
        const float* __restrict__ kb, float* __restrict__ scores){
    __shared__ float at[32][132];
    __shared__ float bt[32][132];
    int bx = blockIdx.x & 31;
    int by = blockIdx.x >> 5;
    int r0 = by*128, c0 = bx*128;
    int tid = threadIdx.x;
    int tx = tid & 15, ty = tid >> 4;
    float acc[8][8] = {};
    for (int k0 = 0; k0 < 128; k0 += 32){
        __syncthreads();
        #pragma unroll
        for (int l=0; l<4; l++){
            int idx = tid + l*256;
            int rowi = idx >> 3;
            int kq  = (idx & 7) * 4;
            float4 a = *(const float4*)&q [(size_t)(r0+rowi)*128 + k0 + kq];
            float4 b = *(const float4*)&kb[(size_t)(c0+rowi)*128 + k0 + kq];
            at[kq+0][rowi]=a.x; at[kq+1][rowi]=a.y; at[kq+2][rowi]=a.z; at[kq+3][rowi]=a.w;
            bt[kq+0][rowi]=b.x; bt[kq+1][rowi]=b.y; bt[kq+2][rowi]=b.z; bt[kq+3][rowi]=b.w;
        }
        __syncthreads();
        #pragma unroll
        for (int k=0;k<32;k++){
            float4 a0 = *(const float4*)&at[k][ty*4];
            float4 a1 = *(const float4*)&at[k][64+ty*4];
            float4 b0 = *(const float4*)&bt[k][tx*4];
            float4 b1 = *(const float4*)&bt[k][64+tx*4];
            float av[8] = {a0.x,a0.y,a0.z,a0.w,a1.x,a1.y,a1.z,a1.w};
            float bv[8] = {b0.x,b0.y,b0.z,b0.w,b1.x,b1.y,b1.z,b1.w};
            #pragma unroll
            for (int u=0;u<8;u++){
                #pragma unroll
                for (int v=0;v<8;v++) acc[u][v] += av[u]*bv[v];
            }
        }
    }
    #pragma unroll
    for (int u=0;u<8;u++){
        int rr = r0 + ((u<4)? ty*4+u : 64+ty*4+(u-4));
        float4 s0 = {acc[u][0],acc[u][1],acc[u][2],acc[u][3]};
        float4 s1 = {acc[u][4],acc[u][5],acc[u][6],acc[u][7]};
        *(float4*)&scores[(size_t)rr*NN + c0 + tx*4] = s0;
        *(float4*)&scores[(size_t)rr*NN + c0 + 64 + tx*4] = s1;
    }
}

// ---------- phase 5b: row max -> 1/max ----------
__global__ __launch_bounds__(256) void k_rowmax(const float* __restrict__ scores, float* __restrict__ invrow){
    __shared__ float sd[256];
    int i = blockIdx.x, tid = threadIdx.x;
    float m = -INFINITY;
    const float4* r = (const float4*)(scores + (size_t)i*NN);
    for (int j=tid;j<NN/4;j+=256){
        float4 v = r[j];
        m = fmaxf(m, fmaxf(fmaxf(v.x,v.y), fmaxf(v.z,v.w)));
    }
    sd[tid]=m; __syncthreads();
    for (int s=128;s>0;s>>=1){ if (tid<s) sd[tid]=fmaxf(sd[tid],sd[tid+s]); __syncthreads(); }
    if (tid==0) invrow[i] = 1.0f / sd[0];
}

// ---------- phase 6: M = A + oushi + c3 + c5 + c9 (in place over dist), global min/max ----------
__global__ __launch_bounds__(256) void k_mcat(const float* __restrict__ scores,
        const float* __restrict__ invrow, const float* __restrict__ maxd,
        float* __restrict__ distM,
        const float* __restrict__ Wcy3, const float* __restrict__ Wcx3,
        const float* __restrict__ Wcy5, const float* __restrict__ Wcx5,
        const float* __restrict__ Wcy9, const float* __restrict__ Wcx9,
        const float* __restrict__ bcy3, const float* __restrict__ bcx3,
        const float* __restrict__ bcy5, const float* __restrict__ bcx5,
        const float* __restrict__ bcy9, const float* __restrict__ bcx9,
        unsigned* __restrict__ gmm){
    __shared__ float As[40][73];
    __shared__ float smn[256], smx[256];
    int i0 = blockIdx.y*32, j0 = blockIdx.x*64;
    int tid = threadIdx.x;
    float wy3[3],wx3[3],wy5[5],wx5[5],wy9[9],wx9[9];
    #pragma unroll
    for (int t=0;t<3;t++){ wy3[t]=Wcy3[t]; wx3[t]=Wcx3[t]; }
    #pragma unroll
    for (int t=0;t<5;t++){ wy5[t]=Wcy5[t]; wx5[t]=Wcx5[t]; }
    #pragma unroll
    for (int t=0;t<9;t++){ wy9[t]=Wcy9[t]; wx9[t]=Wcx9[t]; }
    float bc3 = bcy3[0]+bcx3[0];
    float bc5 = bcy5[0]+bcx5[0];
    float bc9 = bcy9[0]+bcx9[0];
    for (int idx=tid; idx<40*72; idx+=256){
        int lr = idx/72, lc = idx%72;
        int gr = i0-4+lr, gc = j0-4+lc;
        float v = 0.f;
        if (gr>=0 && gr<NN && gc>=0 && gc<NN)
            v = scores[(size_t)gr*NN+gc]*invrow[gr];
        As[lr][lc] = v;
    }
    __syncthreads();
    int c = tid & 63, g = tid >> 6;
    float v[16];
    #pragma unroll
    for (int t=0;t<16;t++) v[t] = As[g*8+t][c+4];
    float mn = INFINITY, mx = -INFINITY;
    #pragma unroll
    for (int rr=0; rr<8; rr++){
        int r = g*8+rr;
        float h[9];
        #pragma unroll
        for (int u=0;u<9;u++) h[u] = As[r+4][c+u];
        float a = h[4];
        float cy3 = h[3]*wy3[0]+h[4]*wy3[1]+h[5]*wy3[2];
        float cy5 = h[2]*wy5[0]+h[3]*wy5[1]+h[4]*wy5[2]+h[5]*wy5[3]+h[6]*wy5[4];
        float cy9 = 0.f;
        #pragma unroll
        for (int u=0;u<9;u++) cy9 += h[u]*wy9[u];
        float cx3 = v[rr+3]*wx3[0]+v[rr+4]*wx3[1]+v[rr+5]*wx3[2];
        float cx5 = v[rr+2]*wx5[0]+v[rr+3]*wx5[1]+v[rr+4]*wx5[2]+v[rr+5]*wx5[3]+v[rr+6]*wx5[4];
        float cx9 = 0.f;
        #pragma unroll
        for (int u=0;u<9;u++) cx9 += v[rr+u]*wx9[u];
        float c3 = cy3+cx3+bc3;
        float c5 = cy5+cx5+bc5;
        float c9 = cy9+cx9+bc9;
        size_t gi = (size_t)(i0+r)*NN + (j0+c);
        float d = distM[gi];
        float ou = 1.f - d / maxd[i0+r];
        float Mv = a + ou + c3 + c5 + c9;
        distM[gi] = Mv;
        mn = fminf(mn, fminf(fminf(a,ou), fminf(fminf(c3,c5),c9)));
        mx = fmaxf(mx, fmaxf(fmaxf(a,ou), fmaxf(fmaxf(c3,c5),c9)));
    }
    smn[tid]=mn; smx[tid]=mx; __syncthreads();
    for (int s=128;s>0;s>>=1){
        if (tid<s){ smn[tid]=fminf(smn[tid],smn[tid+s]); smx[tid]=fmaxf(smx[tid],smx[tid+s]); }
        __syncthreads();
    }
    if (tid==0){
        atomicMin(&gmm[0], enc_f(smn[0]));
        atomicMax(&gmm[1], enc_f(smx[0]));
    }
}

// ---------- phase 7a: hfin = s*(M@Ot) + 5*o*colsum ----------
__global__ __launch_bounds__(256) void k_hM(const float* __restrict__ M, const float* __restrict__ x0,
        const float* __restrict__ colsum, const unsigned* __restrict__ gmm, float* __restrict__ hfin){
    __shared__ float red[256][4];
    int i = blockIdx.x, tid = threadIdx.x;
    float acc0=0,acc1=0,acc2=0,acc3=0;
    const float* Mr = M + (size_t)i*NN;
    for (int j=tid;j<NN;j+=256){
        float m = Mr[j];
        float4 ot = *(const float4*)&x0[j*8+4];
        acc0 += m*ot.x; acc1 += m*ot.y; acc2 += m*ot.z; acc3 += m*ot.w;
    }
    red[tid][0]=acc0; red[tid][1]=acc1; red[tid][2]=acc2; red[tid][3]=acc3;
    __syncthreads();
    for (int s=128;s>0;s>>=1){
        if (tid<s){
            #pragma unroll
            for (int cc=0;cc<4;cc++) red[tid][cc]+=red[tid+s][cc];
        }
        __syncthreads();
    }
    if (tid<4){
        float mnv = dec_f(gmm[0]), mxv = dec_f(gmm[1]);
        float s = 1.f/(mxv-mnv), o = -mnv*s;
        hfin[i*4+tid] = s*red[0][tid] + 5.f*o*colsum[tid];
    }
}

// ---------- phase 7b: MLP head ----------
__global__ __launch_bounds__(256) void k_mlp(const float* __restrict__ hfin,
        const float* __restrict__ Woff, const float* __restrict__ boff, const float* __restrict__ pw,
        const float* __restrict__ Wf1, const float* __restrict__ bf1,
        const float* __restrict__ Wf2, const float* __restrict__ bf2,
        const float* __restrict__ Wf3, const float* __restrict__ bf3,
        float* __restrict__ out){
    __shared__ float h1[8][128];
    __shared__ float h2[8][256];
    __shared__ float h3[8][256];
    __shared__ float4 red4[256];
    int n0 = blockIdx.x*8, tid = threadIdx.x;
    float p = pw[0];
    {
        int c = tid & 127, mb = (tid>>7)*4;
        #pragma unroll
        for (int mm=0; mm<4; mm++){
            int m = mb+mm;
            float v = boff[c];
            #pragma unroll
            for (int k=0;k<4;k++) v += hfin[(n0+m)*4+k]*Woff[k*128+c];
            h1[m][c] = v>0.f ? v : p*v;
        }
    }
    __syncthreads();
    {
        int c = tid;
        float acc[8];
        #pragma unroll
        for (int m=0;m<8;m++) acc[m] = bf1[c];
        for (int k=0;k<128;k++){
            float w = Wf1[k*256+c];
            #pragma unroll
            for (int m=0;m<8;m++) acc[m] += h1[m][k]*w;
        }
        #pragma unroll
        for (int m=0;m<8;m++) h2[m][c] = acc[m]>0.f?acc[m]:0.f;
    }
    __syncthreads();
    {
        int c = tid;
        float acc[8];
        #pragma unroll
        for (int m=0;m<8;m++) acc[m] = bf2[c];
        for (int k=0;k<256;k++){
            float w = Wf2[k*256+c];
            #pragma unroll
            for (int m=0;m<8;m++) acc[m] += h2[m][k]*w;
        }
        #pragma unroll
        for (int m=0;m<8;m++) h3[m][c] = acc[m]>0.f?acc[m]:0.f;
    }
    __syncthreads();
    float w3_0 = Wf3[tid*4+0], w3_1 = Wf3[tid*4+1], w3_2 = Wf3[tid*4+2], w3_3 = Wf3[tid*4+3];
    for (int m=0;m<8;m++){
        float hv = h3[m][tid];
        float4 r; r.x = hv*w3_0; r.y = hv*w3_1; r.z = hv*w3_2; r.w = hv*w3_3;
        red4[tid]=r; __syncthreads();
        for (int s=128;s>0;s>>=1){
            if(tid<s){
                red4[tid].x+=red4[tid+s].x; red4[tid].y+=red4[tid+s].y;
                red4[tid].z+=red4[tid+s].z; red4[tid].w+=red4[tid+s].w;
            }
            __syncthreads();
        }
        if (tid==0){
            float4 o;
            o.x = red4[0].x + bf3[0]; o.y = red4[0].y + bf3[1];
            o.z = red4[0].z + bf3[2]; o.w = red4[0].w + bf3[3];
            *(float4*)&out[(n0+m)*4] = o;
        }
        __syncthreads();
    }
}

// ---------- host ----------
extern "C" void kernel_launch(void* const* d_in, const int* in_sizes, int n_in,
                              void* d_out, int out_size, void* d_ws, size_t ws_size,
                              hipStream_t stream){
    const float* dx1  = (const float*)d_in[0];
    const float* dx2  = (const float*)d_in[1];
    const float* Wk   = (const float*)d_in[2];
    const float* bk   = (const float*)d_in[3];
    const float* Wg1  = (const float*)d_in[4];
    const float* bg1  = (const float*)d_in[5];
    const float* Wg2  = (const float*)d_in[6];
    const float* bg2  = (const float*)d_in[7];
    const float* Wq   = (const float*)d_in[8];
    const float* bq   = (const float*)d_in[9];
    const float* Wkey = (const float*)d_in[10];
    const float* bkey = (const float*)d_in[11];
    const float* Woff = (const float*)d_in[12];
    const float* boff = (const float*)d_in[13];
    const float* pw   = (const float*)d_in[14];
    const float* Wf1  = (const float*)d_in[15];
    const float* bf1  = (const float*)d_in[16];
    const float* Wf2  = (const float*)d_in[17];
    const float* bf2  = (const float*)d_in[18];
    const float* Wf3  = (const float*)d_in[19];
    const float* bf3  = (const float*)d_in[20];
    const float* Wcy3 = (const float*)d_in[21];
    const float* bcy3 = (const float*)d_in[22];
    const float* Wcx3 = (const float*)d_in[23];
    const float* bcx3 = (const float*)d_in[24];
    const float* Wcy5 = (const float*)d_in[25];
    const float* bcy5 = (const float*)d_in[26];
    const float* Wcx5 = (const float*)d_in[27];
    const float* bcx5 = (const float*)d_in[28];
    const float* Wcy9 = (const float*)d_in[29];
    const float* bcy9 = (const float*)d_in[30];
    const float* Wcx9 = (const float*)d_in[31];
    const float* bcx9 = (const float*)d_in[32];

    char* ws = (char*)d_ws;
    size_t off = 0;
    auto alloc = [&](size_t b)->size_t{ size_t o = off; off += (b + 255) & ~(size_t)255; return o; };
    float* x0     = (float*)(ws + alloc((size_t)NN*8*4));
    float* colsum = (float*)(ws + alloc(4*4));
    float* dist   = (float*)(ws + alloc((size_t)NN*NN*4));   // becomes M in place
    float* maxd   = (float*)(ws + alloc((size_t)NN*4));
    int*   nbr    = (int*)  (ws + alloc((size_t)NN*9*4));
    float* deg3   = (float*)(ws + alloc((size_t)NN*4));
    float* deg5   = (float*)(ws + alloc((size_t)NN*4));
    float* deg9   = (float*)(ws + alloc((size_t)NN*4));
    float* y1     = (float*)(ws + alloc((size_t)NN*64*4));
    float* acc1   = (float*)(ws + alloc((size_t)NN*64*4));
    float* h1b    = (float*)(ws + alloc((size_t)NN*64*4));
    float* y2     = (float*)(ws + alloc((size_t)NN*128*4));
    float* acc2   = (float*)(ws + alloc((size_t)NN*128*4));
    float* emb    = (float*)(ws + alloc((size_t)NN*384*4));
    float* qb     = (float*)(ws + alloc((size_t)NN*128*4));
    float* kb     = (float*)(ws + alloc((size_t)NN*128*4));
    float* scores = (float*)(ws + alloc((size_t)NN*NN*4));
    float* invrow = (float*)(ws + alloc((size_t)NN*4));
    unsigned* gmm = (unsigned*)(ws + alloc(2*4));
    float* hfin   = (float*)(ws + alloc((size_t)NN*4*4));
    (void)ws_size; (void)in_sizes; (void)n_in; (void)out_size;

    hipMemsetAsync(colsum, 0, 16, stream);
    hipMemsetAsync(gmm, 0xFF, 4, stream);        // min slot -> 0xFFFFFFFF
    hipMemsetAsync(gmm+1, 0x00, 4, stream);      // max slot -> 0

    k_prep<<<16,256,0,stream>>>(dx1,dx2,Wk,bk,x0,colsum);
    k_dist<<<NN,256,0,stream>>>(dx1,dist,maxd,nbr);
    k_deg_init<<<16,256,0,stream>>>(deg3,deg5,deg9);
    k_deg<<<16,256,0,stream>>>(nbr,deg3,deg5,deg9);

    const int kks[3] = {3,5,9};
    float* degs[3] = {deg3,deg5,deg9};
    for (int g=0; g<3; g++){
        int kk = kks[g];
        float* deg = degs[g];
        k_gcn1_xw<<<NN*64/256,256,0,stream>>>(x0,Wg1,deg,y1);
        hipMemsetAsync(acc1,0,(size_t)NN*64*4,stream);
        k_scat<<<(NN*kk*64)/256,256,0,stream>>>(nbr,y1,acc1,kk,6,NN*kk);
        k_gcn1_fin<<<NN*64/256,256,0,stream>>>(y1,acc1,bg1,deg,h1b);
        k_gcn2_xw<<<NN*128/256,256,0,stream>>>(h1b,Wg2,deg,y2);
        hipMemsetAsync(acc2,0,(size_t)NN*128*4,stream);
        k_scat<<<(NN*kk*128)/256,256,0,stream>>>(nbr,y2,acc2,kk,7,NN*kk);
        k_gcn2_fin<<<NN,128,0,stream>>>(y2,acc2,bg2,deg,emb,g*128);
    }

    k_qk<<<NN/8,256,0,stream>>>(emb,Wq,bq,Wkey,bkey,qb,kb);
    k_scores<<<1024,256,0,stream>>>(qb,kb,scores);
    k_rowmax<<<NN,256,0,stream>>>(scores,invrow);
    k_mcat<<<dim3(64,128),256,0,stream>>>(scores,invrow,maxd,dist,
        Wcy3,Wcx3,Wcy5,Wcx5,Wcy9,Wcx9,
        bcy3,bcx3,bcy5,bcx5,bcy9,bcx9, gmm);
    k_hM<<<NN,256,0,stream>>>(dist,x0,colsum,gmm,hfin);
    k_mlp<<<NN/8,256,0,stream>>>(hfin,Woff,boff,pw,Wf1,bf1,Wf2,bf2,Wf3,bf3,(float*)d_out);
}

// Round 2
// 491.289 us; speedup vs baseline: 1.2385x; 1.2385x over previous
//
#include <hip/hip_runtime.h>
#include <math.h>

#define NN 4096

static __device__ __forceinline__ unsigned enc_f(float f){
    unsigned u = __float_as_uint(f);
    return (u & 0x80000000u) ? ~u : (u | 0x80000000u);
}
static __device__ __forceinline__ float dec_f(unsigned u){
    unsigned b = (u & 0x80000000u) ? (u & 0x7fffffffu) : ~u;
    return __uint_as_float(b);
}

// ---------- phase 1: x0 assembly + Ot column sums ----------
__global__ void k_prep(const float* __restrict__ dx1, const float* __restrict__ dx2,
                       const float* __restrict__ Wk, const float* __restrict__ bk,
                       float* __restrict__ x0, float* __restrict__ colsum){
    int n = blockIdx.x*blockDim.x + threadIdx.x;
    if (n >= NN) return;
    float wk[8];
    #pragma unroll
    for (int j=0;j<8;j++) wk[j] = Wk[j];
    float bkv = bk[0];
    #pragma unroll
    for (int c=0;c<4;c++) x0[n*8+c] = dx1[n*4+c];
    #pragma unroll
    for (int c=0;c<4;c++){
        float acc = bkv;
        #pragma unroll
        for (int j=0;j<8;j++) acc += dx2[(n*8+j)*4+c]*wk[j];
        x0[n*8+4+c] = acc;
        atomicAdd(&colsum[c], acc);
    }
}

// ---------- phase 2: row max dist + top-9 knn (wave per row, no dist array) ----------
__global__ __launch_bounds__(256) void k_dist(const float* __restrict__ dx1,
        float* __restrict__ maxd, int* __restrict__ nbr,
        float* __restrict__ deg3, float* __restrict__ deg5, float* __restrict__ deg9){
    __shared__ float2 ps[NN];
    int tid = threadIdx.x;
    for (int j=tid; j<NN; j+=256){
        float4 v = *(const float4*)&dx1[j*4];
        ps[j] = make_float2(v.x, v.y);
    }
    __syncthreads();
    int lane = tid & 63;
    int i = blockIdx.x*4 + (tid>>6);
    float2 pi = ps[i];
    unsigned long long best[9];
    #pragma unroll
    for (int q=0;q<9;q++) best[q] = ~0ULL;
    float lmax = 0.f;
    for (int t=0;t<64;t++){
        int j = (t<<6) | lane;
        float2 p = ps[j];
        float dx = pi.x - p.x, dy = pi.y - p.y;
        float d = sqrtf(dx*dx + dy*dy);
        lmax = fmaxf(lmax, d);
        unsigned long long cand = ((unsigned long long)__float_as_uint(d) << 32) | (unsigned)j;
        if (j != i && cand < best[8]){
            best[8] = cand;
            #pragma unroll
            for (int q=8; q>0; --q){
                if (best[q] < best[q-1]){ unsigned long long tm=best[q]; best[q]=best[q-1]; best[q-1]=tm; }
            }
        }
    }
    #pragma unroll
    for (int m=1;m<64;m<<=1) lmax = fmaxf(lmax, __shfl_xor(lmax, m, 64));
    if (lane==0) maxd[i] = lmax;
    for (int t=0;t<9;t++){
        unsigned long long w = best[0];
        #pragma unroll
        for (int m=1;m<64;m<<=1){
            unsigned long long o = __shfl_xor(w, m, 64);
            if (o < w) w = o;
        }
        if (best[0] == w){
            #pragma unroll
            for (int q=0;q<8;q++) best[q] = best[q+1];
            best[8] = ~0ULL;
        }
        if (lane==0){
            int j = (int)(w & 0xffffffffu);
            nbr[i*9+t] = j;
            atomicAdd(&deg9[j], 1.f);
            if (t<5) atomicAdd(&deg5[j], 1.f);
            if (t<3) atomicAdd(&deg3[j], 1.f);
        }
    }
}

// ---------- phase 3: GCN (batched over k=3,5,9) ----------
__global__ void k_y1(const float* __restrict__ x0, const float* __restrict__ Wg1,
        const float* __restrict__ deg3, const float* __restrict__ deg5, const float* __restrict__ deg9,
        float* __restrict__ y1){
    int idx = blockIdx.x*256 + threadIdx.x;
    if (idx >= NN*64) return;
    int n = idx>>6, c = idx&63;
    float acc = 0.f;
    #pragma unroll
    for (int k=0;k<8;k++) acc += x0[n*8+k]*Wg1[k*64+c];
    y1[idx]            = acc*rsqrtf(deg3[n]+1.f);
    y1[NN*64+idx]      = acc*rsqrtf(deg5[n]+1.f);
    y1[2*NN*64+idx]    = acc*rsqrtf(deg9[n]+1.f);
}
__global__ void k_scat1(const int* __restrict__ nbr, const float* __restrict__ y1,
                        float* __restrict__ acc1){
    int gid = blockIdx.x*256 + threadIdx.x;
    if (gid >= NN*9*16) return;
    int c4 = (gid & 15)*4;
    int e  = gid >> 4;
    int i = e/9, t = e - i*9;
    int j = nbr[e];
    int gmin = t<3 ? 0 : (t<5 ? 1 : 2);
    for (int g=gmin; g<3; g++){
        float4 y = *(const float4*)&y1[(size_t)g*NN*64 + i*64 + c4];
        float* a = &acc1[(size_t)g*NN*64 + (size_t)j*64 + c4];
        atomicAdd(a+0,y.x); atomicAdd(a+1,y.y); atomicAdd(a+2,y.z); atomicAdd(a+3,y.w);
    }
}
__global__ __launch_bounds__(256) void k_h1y2(const float* __restrict__ y1, const float* __restrict__ acc1,
        const float* __restrict__ bg1, const float* __restrict__ Wg2,
        const float* __restrict__ deg3, const float* __restrict__ deg5, const float* __restrict__ deg9,
        float* __restrict__ y2){
    __shared__ float h1s[12][64];
    int n0 = blockIdx.x*4, tid = threadIdx.x;
    for (int s=tid; s<768; s+=256){
        int p = s>>6, k = s&63;
        int g = p>>2, nl = p&3, n = n0+nl;
        const float* dg = g==0?deg3:(g==1?deg5:deg9);
        float dv = rsqrtf(dg[n]+1.f);
        size_t idx = (size_t)g*NN*64 + (size_t)n*64 + k;
        float v = dv*(y1[idx]+acc1[idx]) + bg1[k];
        h1s[p][k] = v>0.f ? v : 0.f;
    }
    __syncthreads();
    int c = tid & 127, ph = tid>>7;
    float a6[6] = {0,0,0,0,0,0};
    for (int k=0;k<64;k++){
        float w = Wg2[k*128+c];
        #pragma unroll
        for (int q=0;q<6;q++) a6[q] += h1s[q*2+ph][k]*w;
    }
    #pragma unroll
    for (int q=0;q<6;q++){
        int p = q*2+ph, g = p>>2, nl = p&3, n = n0+nl;
        const float* dg = g==0?deg3:(g==1?deg5:deg9);
        float dv = rsqrtf(dg[n]+1.f);
        y2[(size_t)g*NN*128 + (size_t)n*128 + c] = dv*a6[q];
    }
}
__global__ void k_scat2(const int* __restrict__ nbr, const float* __restrict__ y2,
                        float* __restrict__ acc2){
    int gid = blockIdx.x*256 + threadIdx.x;
    if (gid >= NN*9*32) return;
    int c4 = (gid & 31)*4;
    int e  = gid >> 5;
    int i = e/9, t = e - i*9;
    int j = nbr[e];
    int gmin = t<3 ? 0 : (t<5 ? 1 : 2);
    for (int g=gmin; g<3; g++){
        float4 y = *(const float4*)&y2[(size_t)g*NN*128 + (size_t)i*128 + c4];
        float* a = &acc2[(size_t)g*NN*128 + (size_t)j*128 + c4];
        atomicAdd(a+0,y.x); atomicAdd(a+1,y.y); atomicAdd(a+2,y.z); atomicAdd(a+3,y.w);
    }
}
__global__ __launch_bounds__(128) void k_fin(const float* __restrict__ y2, const float* __restrict__ acc2,
        const float* __restrict__ bg2,
        const float* __restrict__ deg3, const float* __restrict__ deg5, const float* __restrict__ deg9,
        float* __restrict__ emb){
    __shared__ float sm[2], ss[2];
    int b = blockIdx.x;
    int n = b & (NN-1), g = b >> 12;
    const float* dg = g==0?deg3:(g==1?deg5:deg9);
    int c = threadIdx.x;
    size_t idx = (size_t)g*NN*128 + (size_t)n*128 + c;
    float dv = rsqrtf(dg[n]+1.f);
    float v = dv*(y2[idx]+acc2[idx]) + bg2[c];
    float m = v;
    #pragma unroll
    for (int s=1;s<64;s<<=1) m = fmaxf(m, __shfl_xor(m, s, 64));
    if ((c&63)==0) sm[c>>6] = m;
    __syncthreads();
    m = fmaxf(sm[0], sm[1]);
    float e = expf(v - m);
    float t = e;
    #pragma unroll
    for (int s=1;s<64;s<<=1) t += __shfl_xor(t, s, 64);
    if ((c&63)==0) ss[c>>6] = t;
    __syncthreads();
    t = ss[0]+ss[1];
    emb[n*384 + g*128 + c] = v - m - logf(t);
}

// ---------- phase 4: q/k projections ----------
__global__ __launch_bounds__(256) void k_qk(const float* __restrict__ emb,
        const float* __restrict__ Wq, const float* __restrict__ bq,
        const float* __restrict__ Wkey, const float* __restrict__ bkey,
        float* __restrict__ q, float* __restrict__ kbuf){
    __shared__ float es[8][384];
    int n0 = blockIdx.x*8;
    int tid = threadIdx.x;
    for (int idx=tid; idx<8*384; idx+=256){
        int m = idx/384, k = idx%384;
        es[m][k] = emb[(n0+m)*384+k];
    }
    __syncthreads();
    int c = tid & 127;
    int sel = tid >> 7;
    const float* W = sel ? Wkey : Wq;
    float b = sel ? bkey[c] : bq[c];
    float acc[8];
    #pragma unroll
    for (int m=0;m<8;m++) acc[m]=b;
    for (int k=0;k<384;k++){
        float w = W[k*128+c];
        #pragma unroll
        for (int m=0;m<8;m++) acc[m] += es[m][k]*w;
    }
    float* out = sel ? kbuf : q;
    #pragma unroll
    for (int m=0;m<8;m++) out[(n0+m)*128+c] = acc[m];
}

// ---------- phase 5: scores = q @ k^T + fused per-row max ----------
__global__ __launch_bounds__(256) void k_scores(const float* __restrict__ q,
        const float* __restrict__ kb, float* __restrict__ scores,
        unsigned* __restrict__ rowmaxenc){
    __shared__ float at[32][132];
    __shared__ float bt[32][132];
    int bx = blockIdx.x & 31;
    int by = blockIdx.x >> 5;
    int r0 = by*128, c0 = bx*128;
    int tid = threadIdx.x;
    int tx = tid & 15, ty = tid >> 4;
    float acc[8][8] = {};
    for (int k0 = 0; k0 < 128; k0 += 32){
        __syncthreads();
        #pragma unroll
        for (int l=0; l<4; l++){
            int idx = tid + l*256;
            int rowi = idx >> 3;
            int kq  = (idx & 7) * 4;
            float4 a = *(const float4*)&q [(size_t)(r0+rowi)*128 + k0 + kq];
            float4 b = *(const float4*)&kb[(size_t)(c0+rowi)*128 + k0 + kq];
            at[kq+0][rowi]=a.x; at[kq+1][rowi]=a.y; at[kq+2][rowi]=a.z; at[kq+3][rowi]=a.w;
            bt[kq+0][rowi]=b.x; bt[kq+1][rowi]=b.y; bt[kq+2][rowi]=b.z; bt[kq+3][rowi]=b.w;
        }
        __syncthreads();
        #pragma unroll
        for (int k=0;k<32;k++){
            float4 a0 = *(const float4*)&at[k][ty*4];
            float4 a1 = *(const float4*)&at[k][64+ty*4];
            float4 b0 = *(const float4*)&bt[k][tx*4];
            float4 b1 = *(const float4*)&bt[k][64+tx*4];
            float av[8] = {a0.x,a0.y,a0.z,a0.w,a1.x,a1.y,a1.z,a1.w};
            float bv[8] = {b0.x,b0.y,b0.z,b0.w,b1.x,b1.y,b1.z,b1.w};
            #pragma unroll
            for (int u=0;u<8;u++){
                #pragma unroll
                for (int v=0;v<8;v++) acc[u][v] += av[u]*bv[v];
            }
        }
    }
    #pragma unroll
    for (int u=0;u<8;u++){
        int rr = r0 + ((u<4)? ty*4+u : 64+ty*4+(u-4));
        float4 s0 = {acc[u][0],acc[u][1],acc[u][2],acc[u][3]};
        float4 s1 = {acc[u][4],acc[u][5],acc[u][6],acc[u][7]};
        *(float4*)&scores[(size_t)rr*NN + c0 + tx*4] = s0;
        *(float4*)&scores[(size_t)rr*NN + c0 + 64 + tx*4] = s1;
        float m = acc[u][0];
        #pragma unroll
        for (int v=1;v<8;v++) m = fmaxf(m, acc[u][v]);
        #pragma unroll
        for (int s=1;s<16;s<<=1) m = fmaxf(m, __shfl_xor(m, s, 64));
        if (tx==0) atomicMax(&rowmaxenc[rr], enc_f(m));
    }
}

// ---------- phase 6: fused A/oushi/convs + M@Ot partials + minmax ----------
__global__ __launch_bounds__(256) void k_mcat(const float* __restrict__ scores,
        const unsigned* __restrict__ rowmaxenc, const float* __restrict__ maxd,
        const float* __restrict__ dx1, const float* __restrict__ x0,
        const float* __restrict__ Wcy3, const float* __restrict__ Wcx3,
        const float* __restrict__ Wcy5, const float* __restrict__ Wcx5,
        const float* __restrict__ Wcy9, const float* __restrict__ Wcx9,
        const float* __restrict__ bcy3, const float* __restrict__ bcx3,
        const float* __restrict__ bcy5, const float* __restrict__ bcx5,
        const float* __restrict__ bcy9, const float* __restrict__ bcx9,
        float* __restrict__ mnmx, float* __restrict__ hpart){
    __shared__ float As[40][76];
    __shared__ float invr[40];
    __shared__ float2 pj[64];
    __shared__ float4 ots[64];
    __shared__ float2 pi[32];
    __shared__ float im[32];
    __shared__ float smn[256], smx[256];
    int xb = blockIdx.x, yb = blockIdx.y;
    int i0 = yb*32, j0 = xb*64;
    int tid = threadIdx.x;
    float wy3[3],wx3[3],wy5[5],wx5[5],wy9[9],wx9[9];
    #pragma unroll
    for (int t=0;t<3;t++){ wy3[t]=Wcy3[t]; wx3[t]=Wcx3[t]; }
    #pragma unroll
    for (int t=0;t<5;t++){ wy5[t]=Wcy5[t]; wx5[t]=Wcx5[t]; }
    #pragma unroll
    for (int t=0;t<9;t++){ wy9[t]=Wcy9[t]; wx9[t]=Wcx9[t]; }
    float bc3 = bcy3[0]+bcx3[0];
    float bc5 = bcy5[0]+bcx5[0];
    float bc9 = bcy9[0]+bcx9[0];
    if (tid < 40){
        int gr = i0-4+tid;
        invr[tid] = ((unsigned)gr < NN) ? 1.f/dec_f(rowmaxenc[gr]) : 0.f;
    } else if (tid >= 64 && tid < 128){
        int c = tid-64, j = j0+c;
        float4 v = *(const float4*)&dx1[j*4];
        pj[c] = make_float2(v.x, v.y);
        ots[c] = *(const float4*)&x0[j*8+4];
    } else if (tid >= 128 && tid < 160){
        int r = tid-128;
        float4 v = *(const float4*)&dx1[(i0+r)*4];
        pi[r] = make_float2(v.x, v.y);
        im[r] = 1.f/maxd[i0+r];
    }
    __syncthreads();
    for (int idx=tid; idx<40*72; idx+=256){
        int lr = idx/72, lc = idx - lr*72;
        int gr = i0-4+lr, gc = j0-4+lc;
        float v = 0.f;
        if ((unsigned)gr < NN && (unsigned)gc < NN)
            v = scores[(size_t)gr*NN + gc]*invr[lr];
        As[lr][lc] = v;
    }
    __syncthreads();
    int r = tid>>3, cb = tid&7, c0l = cb*8;
    float acc9[8]={0,0,0,0,0,0,0,0}, acc5[8]={0,0,0,0,0,0,0,0}, acc3[8]={0,0,0,0,0,0,0,0}, ctr[8];
    #pragma unroll
    for (int u=0;u<9;u++){
        float4 a = *(const float4*)&As[r+u][c0l+4];
        float4 b = *(const float4*)&As[r+u][c0l+8];
        float vals[8] = {a.x,a.y,a.z,a.w,b.x,b.y,b.z,b.w};
        #pragma unroll
        for (int q=0;q<8;q++){
            acc9[q] += vals[q]*wx9[u];
            if (u>=2 && u<=6) acc5[q] += vals[q]*wx5[u-2];
            if (u>=3 && u<=5) acc3[q] += vals[q]*wx3[u-3];
            if (u==4) ctr[q] = vals[q];
        }
    }
    float win[16];
    #pragma unroll
    for (int q4=0;q4<4;q4++){
        float4 w4 = *(const float4*)&As[r+4][c0l+q4*4];
        win[q4*4+0]=w4.x; win[q4*4+1]=w4.y; win[q4*4+2]=w4.z; win[q4*4+3]=w4.w;
    }
    float mn = INFINITY, mx = -INFINITY;
    float pd0=0,pd1=0,pd2=0,pd3=0;
    float2 ppi = pi[r];
    float imv = im[r];
    #pragma unroll
    for (int q=0;q<8;q++){
        float cy9=0.f;
        #pragma unroll
        for (int u=0;u<9;u++) cy9 += win[q+u]*wy9[u];
        float cy5=0.f;
        #pragma unroll
        for (int u=0;u<5;u++) cy5 += win[q+2+u]*wy5[u];
        float cy3=0.f;
        #pragma unroll
        for (int u=0;u<3;u++) cy3 += win[q+3+u]*wy3[u];
        float c3v = cy3+acc3[q]+bc3;
        float c5v = cy5+acc5[q]+bc5;
        float c9v = cy9+acc9[q]+bc9;
        float a = ctr[q];
        float2 pjv = pj[c0l+q];
        float dxp = ppi.x-pjv.x, dyp = ppi.y-pjv.y;
        float ou = 1.f - sqrtf(dxp*dxp+dyp*dyp)*imv;
        float Mv = a + ou + c3v + c5v + c9v;
        mn = fminf(mn, fminf(fminf(a,ou), fminf(fminf(c3v,c5v),c9v)));
        mx = fmaxf(mx, fmaxf(fmaxf(a,ou), fmaxf(fmaxf(c3v,c5v),c9v)));
        float4 ot = ots[c0l+q];
        pd0 += Mv*ot.x; pd1 += Mv*ot.y; pd2 += Mv*ot.z; pd3 += Mv*ot.w;
    }
    #pragma unroll
    for (int m=1;m<8;m<<=1){
        pd0 += __shfl_xor(pd0, m, 64);
        pd1 += __shfl_xor(pd1, m, 64);
        pd2 += __shfl_xor(pd2, m, 64);
        pd3 += __shfl_xor(pd3, m, 64);
    }
    if (cb==0){
        float4 pd = {pd0,pd1,pd2,pd3};
        *(float4*)&hpart[((size_t)(i0+r)*64 + xb)*4] = pd;
    }
    smn[tid]=mn; smx[tid]=mx; __syncthreads();
    for (int s=128;s>0;s>>=1){
        if (tid<s){ smn[tid]=fminf(smn[tid],smn[tid+s]); smx[tid]=fmaxf(smx[tid],smx[tid+s]); }
        __syncthreads();
    }
    if (tid==0){
        int bid = yb*64 + xb;
        mnmx[bid] = smn[0];
        mnmx[8192 + bid] = smx[0];
    }
}

// ---------- phase 6b: reduce per-block minmax ----------
__global__ __launch_bounds__(256) void k_gmm(const float* __restrict__ mnmx, float* __restrict__ gmm){
    __shared__ float smn[256], smx[256];
    int tid = threadIdx.x;
    float mn = INFINITY, mx = -INFINITY;
    for (int i=tid; i<8192; i+=256){
        mn = fminf(mn, mnmx[i]);
        mx = fmaxf(mx, mnmx[8192+i]);
    }
    smn[tid]=mn; smx[tid]=mx; __syncthreads();
    for (int s=128;s>0;s>>=1){
        if (tid<s){ smn[tid]=fminf(smn[tid],smn[tid+s]); smx[tid]=fmaxf(smx[tid],smx[tid+s]); }
        __syncthreads();
    }
    if (tid==0){ gmm[0]=smn[0]; gmm[1]=smx[0]; }
}

// ---------- phase 7a: reduce partials + affine ----------
__global__ __launch_bounds__(256) void k_hred(const float* __restrict__ hpart,
        const float* __restrict__ gmm, const float* __restrict__ colsum,
        float* __restrict__ hfin){
    int i = blockIdx.x*256 + threadIdx.x;
    if (i >= NN) return;
    float4 sum = {0,0,0,0};
    const float4* hp = (const float4*)hpart + (size_t)i*64;
    for (int xb=0; xb<64; xb++){
        float4 v = hp[xb];
        sum.x+=v.x; sum.y+=v.y; sum.z+=v.z; sum.w+=v.w;
    }
    float mnv = gmm[0], mxv = gmm[1];
    float s = 1.f/(mxv-mnv), o = -mnv*s;
    float4 cs = *(const float4*)colsum;
    float4 out;
    out.x = s*sum.x + 5.f*o*cs.x;
    out.y = s*sum.y + 5.f*o*cs.y;
    out.z = s*sum.z + 5.f*o*cs.z;
    out.w = s*sum.w + 5.f*o*cs.w;
    *(float4*)&hfin[i*4] = out;
}

// ---------- phase 7b: MLP head ----------
__global__ __launch_bounds__(256) void k_mlp(const float* __restrict__ hfin,
        const float* __restrict__ Woff, const float* __restrict__ boff, const float* __restrict__ pw,
        const float* __restrict__ Wf1, const float* __restrict__ bf1,
        const float* __restrict__ Wf2, const float* __restrict__ bf2,
        const float* __restrict__ Wf3, const float* __restrict__ bf3,
        float* __restrict__ out){
    __shared__ float h1[8][128];
    __shared__ float h2[8][256];
    __shared__ float h3[8][256];
    __shared__ float4 red4[256];
    int n0 = blockIdx.x*8, tid = threadIdx.x;
    float p = pw[0];
    {
        int c = tid & 127, mb = (tid>>7)*4;
        #pragma unroll
        for (int mm=0; mm<4; mm++){
            int m = mb+mm;
            float v = boff[c];
            #pragma unroll
            for (int k=0;k<4;k++) v += hfin[(n0+m)*4+k]*Woff[k*128+c];
            h1[m][c] = v>0.f ? v : p*v;
        }
    }
    __syncthreads();
    {
        int c = tid;
        float acc[8];
        #pragma unroll
        for (int m=0;m<8;m++) acc[m] = bf1[c];
        for (int k=0;k<128;k++){
            float w = Wf1[k*256+c];
            #pragma unroll
            for (int m=0;m<8;m++) acc[m] += h1[m][k]*w;
        }
        #pragma unroll
        for (int m=0;m<8;m++) h2[m][c] = acc[m]>0.f?acc[m]:0.f;
    }
    __syncthreads();
    {
        int c = tid;
        float acc[8];
        #pragma unroll
        for (int m=0;m<8;m++) acc[m] = bf2[c];
        for (int k=0;k<256;k++){
            float w = Wf2[k*256+c];
            #pragma unroll
            for (int m=0;m<8;m++) acc[m] += h2[m][k]*w;
        }
        #pragma unroll
        for (int m=0;m<8;m++) h3[m][c] = acc[m]>0.f?acc[m]:0.f;
    }
    __syncthreads();
    float w3_0 = Wf3[tid*4+0], w3_1 = Wf3[tid*4+1], w3_2 = Wf3[tid*4+2], w3_3 = Wf3[tid*4+3];
    for (int m=0;m<8;m++){
        float hv = h3[m][tid];
        float4 r; r.x = hv*w3_0; r.y = hv*w3_1; r.z = hv*w3_2; r.w = hv*w3_3;
        red4[tid]=r; __syncthreads();
        for (int s=128;s>0;s>>=1){
            if(tid<s){
                red4[tid].x+=red4[tid+s].x; red4[tid].y+=red4[tid+s].y;
                red4[tid].z+=red4[tid+s].z; red4[tid].w+=red4[tid+s].w;
            }
            __syncthreads();
        }
        if (tid==0){
            float4 o;
            o.x = red4[0].x + bf3[0]; o.y = red4[0].y + bf3[1];
            o.z = red4[0].z + bf3[2]; o.w = red4[0].w + bf3[3];
            *(float4*)&out[(n0+m)*4] = o;
        }
        __syncthreads();
    }
}

// ---------- host ----------
extern "C" void kernel_launch(void* const* d_in, const int* in_sizes, int n_in,
                              void* d_out, int out_size, void* d_ws, size_t ws_size,
                              hipStream_t stream){
    const float* dx1  = (const float*)d_in[0];
    const float* dx2  = (const float*)d_in[1];
    const float* Wk   = (const float*)d_in[2];
    const float* bk   = (const float*)d_in[3];
    const float* Wg1  = (const float*)d_in[4];
    const float* bg1  = (const float*)d_in[5];
    const float* Wg2  = (const float*)d_in[6];
    const float* bg2  = (const float*)d_in[7];
    const float* Wq   = (const float*)d_in[8];
    const float* bq   = (const float*)d_in[9];
    const float* Wkey = (const float*)d_in[10];
    const float* bkey = (const float*)d_in[11];
    const float* Woff = (const float*)d_in[12];
    const float* boff = (const float*)d_in[13];
    const float* pw   = (const float*)d_in[14];
    const float* Wf1  = (const float*)d_in[15];
    const float* bf1  = (const float*)d_in[16];
    const float* Wf2  = (const float*)d_in[17];
    const float* bf2  = (const float*)d_in[18];
    const float* Wf3  = (const float*)d_in[19];
    const float* bf3  = (const float*)d_in[20];
    const float* Wcy3 = (const float*)d_in[21];
    const float* bcy3 = (const float*)d_in[22];
    const float* Wcx3 = (const float*)d_in[23];
    const float* bcx3 = (const float*)d_in[24];
    const float* Wcy5 = (const float*)d_in[25];
    const float* bcy5 = (const float*)d_in[26];
    const float* Wcx5 = (const float*)d_in[27];
    const float* bcx5 = (const float*)d_in[28];
    const float* Wcy9 = (const float*)d_in[29];
    const float* bcy9 = (const float*)d_in[30];
    const float* Wcx9 = (const float*)d_in[31];
    const float* bcx9 = (const float*)d_in[32];

    char* ws = (char*)d_ws;
    size_t off = 0;
    auto alloc = [&](size_t b)->void*{ void* p = ws + off; off += (b + 255) & ~(size_t)255; return p; };

    // --- zero-init region (one memset) ---
    char* zbase = ws + off;
    float*    colsum    = (float*)   alloc(4*4);
    float*    deg3      = (float*)   alloc((size_t)NN*4);
    float*    deg5      = (float*)   alloc((size_t)NN*4);
    float*    deg9      = (float*)   alloc((size_t)NN*4);
    unsigned* rowmaxenc = (unsigned*)alloc((size_t)NN*4);
    float*    acc1      = (float*)   alloc((size_t)3*NN*64*4);
    float*    acc2      = (float*)   alloc((size_t)3*NN*128*4);
    size_t zbytes = (size_t)((ws + off) - zbase);

    // --- non-zeroed ---
    float* x0     = (float*)alloc((size_t)NN*8*4);
    float* maxd   = (float*)alloc((size_t)NN*4);
    int*   nbr    = (int*)  alloc((size_t)NN*9*4);
    float* y1     = (float*)alloc((size_t)3*NN*64*4);
    float* y2     = (float*)alloc((size_t)3*NN*128*4);
    float* emb    = (float*)alloc((size_t)NN*384*4);
    float* qb     = (float*)alloc((size_t)NN*128*4);
    float* kb     = (float*)alloc((size_t)NN*128*4);
    float* scores = (float*)alloc((size_t)NN*NN*4);
    float* mnmx   = (float*)alloc((size_t)2*8192*4);
    float* hpart  = (float*)alloc((size_t)NN*64*4*4);
    float* gmm    = (float*)alloc(2*4);
    float* hfin   = (float*)alloc((size_t)NN*4*4);
    (void)ws_size; (void)in_sizes; (void)n_in; (void)out_size;

    hipMemsetAsync(zbase, 0, zbytes, stream);

    k_prep<<<16,256,0,stream>>>(dx1,dx2,Wk,bk,x0,colsum);
    k_dist<<<NN/4,256,0,stream>>>(dx1,maxd,nbr,deg3,deg5,deg9);

    k_y1   <<<NN*64/256,256,0,stream>>>(x0,Wg1,deg3,deg5,deg9,y1);
    k_scat1<<<NN*9*16/256,256,0,stream>>>(nbr,y1,acc1);
    k_h1y2 <<<NN/4,256,0,stream>>>(y1,acc1,bg1,Wg2,deg3,deg5,deg9,y2);
    k_scat2<<<NN*9*32/256,256,0,stream>>>(nbr,y2,acc2);
    k_fin  <<<NN*3,128,0,stream>>>(y2,acc2,bg2,deg3,deg5,deg9,emb);

    k_qk<<<NN/8,256,0,stream>>>(emb,Wq,bq,Wkey,bkey,qb,kb);
    k_scores<<<1024,256,0,stream>>>(qb,kb,scores,rowmaxenc);
    k_mcat<<<dim3(64,128),256,0,stream>>>(scores,rowmaxenc,maxd,dx1,x0,
        Wcy3,Wcx3,Wcy5,Wcx5,Wcy9,Wcx9,
        bcy3,bcx3,bcy5,bcx5,bcy9,bcx9, mnmx, hpart);
    k_gmm<<<1,256,0,stream>>>(mnmx,gmm);
    k_hred<<<NN/256,256,0,stream>>>(hpart,gmm,colsum,hfin);
    k_mlp<<<NN/8,256,0,stream>>>(hfin,Woff,boff,pw,Wf1,bf1,Wf2,bf2,Wf3,bf3,(float*)d_out);
}

// Round 3
// 354.669 us; speedup vs baseline: 1.7156x; 1.3852x over previous
//
#include <hip/hip_runtime.h>
#include <math.h>

#define NN 4096

static __device__ __forceinline__ unsigned enc_f(float f){
    unsigned u = __float_as_uint(f);
    return (u & 0x80000000u) ? ~u : (u | 0x80000000u);
}
static __device__ __forceinline__ float dec_f(unsigned u){
    unsigned b = (u & 0x80000000u) ? (u & 0x7fffffffu) : ~u;
    return __uint_as_float(b);
}

// ---------- phase 1: x0 assembly + Ot column sums ----------
__global__ void k_prep(const float* __restrict__ dx1, const float* __restrict__ dx2,
                       const float* __restrict__ Wk, const float* __restrict__ bk,
                       float* __restrict__ x0, float* __restrict__ colsum){
    int n = blockIdx.x*blockDim.x + threadIdx.x;
    if (n >= NN) return;
    float wk[8];
    #pragma unroll
    for (int j=0;j<8;j++) wk[j] = Wk[j];
    float bkv = bk[0];
    #pragma unroll
    for (int c=0;c<4;c++) x0[n*8+c] = dx1[n*4+c];
    #pragma unroll
    for (int c=0;c<4;c++){
        float acc = bkv;
        #pragma unroll
        for (int j=0;j<8;j++) acc += dx2[(n*8+j)*4+c]*wk[j];
        x0[n*8+4+c] = acc;
        atomicAdd(&colsum[c], acc);
    }
}

// ---------- phase 2: row max dist + top-9 knn + int in-degree counts ----------
__global__ __launch_bounds__(256) void k_dist(const float* __restrict__ dx1,
        float* __restrict__ maxd, int* __restrict__ nbr,
        int* __restrict__ cnt3, int* __restrict__ cnt5, int* __restrict__ cnt9){
    __shared__ float2 ps[NN];
    int tid = threadIdx.x;
    for (int j=tid; j<NN; j+=256){
        float4 v = *(const float4*)&dx1[j*4];
        ps[j] = make_float2(v.x, v.y);
    }
    __syncthreads();
    int lane = tid & 63;
    int i = blockIdx.x*4 + (tid>>6);
    float2 pi = ps[i];
    unsigned long long best[9];
    #pragma unroll
    for (int q=0;q<9;q++) best[q] = ~0ULL;
    float lmax = 0.f;
    for (int t=0;t<64;t++){
        int j = (t<<6) | lane;
        float2 p = ps[j];
        float dx = pi.x - p.x, dy = pi.y - p.y;
        float d = sqrtf(dx*dx + dy*dy);
        lmax = fmaxf(lmax, d);
        unsigned long long cand = ((unsigned long long)__float_as_uint(d) << 32) | (unsigned)j;
        if (j != i && cand < best[8]){
            best[8] = cand;
            #pragma unroll
            for (int q=8; q>0; --q){
                if (best[q] < best[q-1]){ unsigned long long tm=best[q]; best[q]=best[q-1]; best[q-1]=tm; }
            }
        }
    }
    #pragma unroll
    for (int m=1;m<64;m<<=1) lmax = fmaxf(lmax, __shfl_xor(lmax, m, 64));
    if (lane==0) maxd[i] = lmax;
    for (int t=0;t<9;t++){
        unsigned long long w = best[0];
        #pragma unroll
        for (int m=1;m<64;m<<=1){
            unsigned long long o = __shfl_xor(w, m, 64);
            if (o < w) w = o;
        }
        if (best[0] == w){
            #pragma unroll
            for (int q=0;q<8;q++) best[q] = best[q+1];
            best[8] = ~0ULL;
        }
        if (lane==0){
            int j = (int)(w & 0xffffffffu);
            nbr[i*9+t] = j;
            atomicAdd(&cnt9[j], 1);
            if (t<5) atomicAdd(&cnt5[j], 1);
            if (t<3) atomicAdd(&cnt3[j], 1);
        }
    }
}

// ---------- phase 2b: CSR offsets (exclusive scan) + dinv ----------
__global__ __launch_bounds__(256) void k_scan(const int* __restrict__ cnt3,
        const int* __restrict__ cnt5, const int* __restrict__ cnt9,
        int* __restrict__ offc, float* __restrict__ dinvc){
    __shared__ int part[256];
    int tid = threadIdx.x;
    for (int g=0; g<3; g++){
        const int* cp = g==0?cnt3:(g==1?cnt5:cnt9);
        int base = tid*16;
        int loc[16]; int s=0;
        #pragma unroll
        for (int q=0;q<16;q++){ loc[q]=s; s += cp[base+q]; }
        part[tid]=s; __syncthreads();
        for (int d=1; d<256; d<<=1){
            int v = (tid>=d) ? part[tid-d] : 0;
            __syncthreads();
            part[tid] += v;
            __syncthreads();
        }
        int pre = (tid==0) ? 0 : part[tid-1];
        #pragma unroll
        for (int q=0;q<16;q++){
            offc[g*NN + base + q]  = pre + loc[q];
            dinvc[g*NN + base + q] = rsqrtf((float)cp[base+q] + 1.f);
        }
        __syncthreads();
    }
}

// ---------- phase 2c: fill reverse-edge lists ----------
__global__ void k_fill(const int* __restrict__ nbr, const int* __restrict__ offc,
        int* __restrict__ cur, int* __restrict__ rev){
    int i = blockIdx.x*256 + threadIdx.x;
    if (i >= NN) return;
    #pragma unroll
    for (int t=0;t<9;t++){
        int j = nbr[i*9+t];
        int gmin = t<3 ? 0 : (t<5 ? 1 : 2);
        for (int g=gmin; g<3; g++){
            int pos = atomicAdd(&cur[g*NN+j], 1);
            int rb = (g==0) ? 0 : (g==1 ? NN*3 : NN*8);
            rev[rb + offc[g*NN+j] + pos] = i;
        }
    }
}

// ---------- phase 3: GCN layer-1 input transform (shared across graphs) ----------
__global__ void k_y1(const float* __restrict__ x0, const float* __restrict__ Wg1,
                     float* __restrict__ xw){
    int idx = blockIdx.x*256 + threadIdx.x;
    if (idx >= NN*64) return;
    int n = idx>>6, c = idx&63;
    float acc = 0.f;
    #pragma unroll
    for (int k=0;k<8;k++) acc += x0[n*8+k]*Wg1[k*64+c];
    xw[idx] = acc;
}

// ---------- phase 3b: gather layer-1 + relu + layer-2 matmul ----------
__global__ __launch_bounds__(256) void k_h1y2(const float* __restrict__ xw,
        const int* __restrict__ offc,
        const int* __restrict__ cnt3, const int* __restrict__ cnt5, const int* __restrict__ cnt9,
        const int* __restrict__ rev, const float* __restrict__ dinvc,
        const float* __restrict__ bg1, const float* __restrict__ Wg2,
        float* __restrict__ y2){
    __shared__ float h1s[12][64];
    int n0 = blockIdx.x*4, tid = threadIdx.x;
    for (int s=tid; s<768; s+=256){
        int p = s>>6, k = s&63, g = p>>2, n = n0+(p&3);
        const int* cp = g==0?cnt3:(g==1?cnt5:cnt9);
        int rb = (g==0) ? 0 : (g==1 ? NN*3 : NN*8);
        int cnt = cp[n];
        int o = rb + offc[g*NN+n];
        float dv = dinvc[g*NN+n];
        float srow = dv*xw[n*64+k];
        for (int e=0;e<cnt;e++){
            int i = rev[o+e];
            srow += dinvc[g*NN+i]*xw[i*64+k];
        }
        float v = dv*srow + bg1[k];
        h1s[p][k] = v>0.f ? v : 0.f;
    }
    __syncthreads();
    int c = tid & 127, ph = tid>>7;
    float a6[6] = {0,0,0,0,0,0};
    for (int k=0;k<64;k++){
        float w = Wg2[k*128+c];
        #pragma unroll
        for (int q=0;q<6;q++) a6[q] += h1s[q*2+ph][k]*w;
    }
    #pragma unroll
    for (int q=0;q<6;q++){
        int p = q*2+ph, g = p>>2, n = n0+(p&3);
        float dv = dinvc[g*NN+n];
        y2[(size_t)g*NN*128 + (size_t)n*128 + c] = dv*a6[q];
    }
}

// ---------- phase 3c: gather layer-2 + bias + log_softmax ----------
__global__ __launch_bounds__(128) void k_fin(const float* __restrict__ y2,
        const int* __restrict__ offc,
        const int* __restrict__ cnt3, const int* __restrict__ cnt5, const int* __restrict__ cnt9,
        const int* __restrict__ rev, const float* __restrict__ dinvc,
        const float* __restrict__ bg2, float* __restrict__ emb){
    __shared__ float sm[2], ss[2];
    int b = blockIdx.x;
    int n = b & (NN-1), g = b >> 12;
    const int* cp = g==0?cnt3:(g==1?cnt5:cnt9);
    int rb = (g==0) ? 0 : (g==1 ? NN*3 : NN*8);
    int cnt = cp[n];
    int o = rb + offc[g*NN+n];
    float dv = dinvc[g*NN+n];
    int c = threadIdx.x;
    const float* yg = y2 + (size_t)g*NN*128;
    float s = yg[(size_t)n*128 + c];
    for (int e=0;e<cnt;e++){
        int i = rev[o+e];
        s += yg[(size_t)i*128 + c];
    }
    float v = dv*s + bg2[c];
    float m = v;
    #pragma unroll
    for (int st=1;st<64;st<<=1) m = fmaxf(m, __shfl_xor(m, st, 64));
    if ((c&63)==0) sm[c>>6] = m;
    __syncthreads();
    m = fmaxf(sm[0], sm[1]);
    float e = expf(v - m);
    float t = e;
    #pragma unroll
    for (int st=1;st<64;st<<=1) t += __shfl_xor(t, st, 64);
    if ((c&63)==0) ss[c>>6] = t;
    __syncthreads();
    t = ss[0]+ss[1];
    emb[n*384 + g*128 + c] = v - m - logf(t);
}

// ---------- phase 4: q/k projections ----------
__global__ __launch_bounds__(256) void k_qk(const float* __restrict__ emb,
        const float* __restrict__ Wq, const float* __restrict__ bq,
        const float* __restrict__ Wkey, const float* __restrict__ bkey,
        float* __restrict__ q, float* __restrict__ kbuf){
    __shared__ float es[8][384];
    int n0 = blockIdx.x*8;
    int tid = threadIdx.x;
    for (int idx=tid; idx<8*384; idx+=256){
        int m = idx/384, k = idx%384;
        es[m][k] = emb[(n0+m)*384+k];
    }
    __syncthreads();
    int c = tid & 127;
    int sel = tid >> 7;
    const float* W = sel ? Wkey : Wq;
    float b = sel ? bkey[c] : bq[c];
    float acc[8];
    #pragma unroll
    for (int m=0;m<8;m++) acc[m]=b;
    for (int k=0;k<384;k++){
        float w = W[k*128+c];
        #pragma unroll
        for (int m=0;m<8;m++) acc[m] += es[m][k]*w;
    }
    float* out = sel ? kbuf : q;
    #pragma unroll
    for (int m=0;m<8;m++) out[(n0+m)*128+c] = acc[m];
}

// ---------- phase 5: scores = q @ k^T + fused per-row max ----------
__global__ __launch_bounds__(256) void k_scores(const float* __restrict__ q,
        const float* __restrict__ kb, float* __restrict__ scores,
        unsigned* __restrict__ rowmaxenc){
    __shared__ float at[32][132];
    __shared__ float bt[32][132];
    int bx = blockIdx.x & 31;
    int by = blockIdx.x >> 5;
    int r0 = by*128, c0 = bx*128;
    int tid = threadIdx.x;
    int tx = tid & 15, ty = tid >> 4;
    float acc[8][8] = {};
    for (int k0 = 0; k0 < 128; k0 += 32){
        __syncthreads();
        #pragma unroll
        for (int l=0; l<4; l++){
            int idx = tid + l*256;
            int rowi = idx >> 3;
            int kq  = (idx & 7) * 4;
            float4 a = *(const float4*)&q [(size_t)(r0+rowi)*128 + k0 + kq];
            float4 b = *(const float4*)&kb[(size_t)(c0+rowi)*128 + k0 + kq];
            at[kq+0][rowi]=a.x; at[kq+1][rowi]=a.y; at[kq+2][rowi]=a.z; at[kq+3][rowi]=a.w;
            bt[kq+0][rowi]=b.x; bt[kq+1][rowi]=b.y; bt[kq+2][rowi]=b.z; bt[kq+3][rowi]=b.w;
        }
        __syncthreads();
        #pragma unroll
        for (int k=0;k<32;k++){
            float4 a0 = *(const float4*)&at[k][ty*4];
            float4 a1 = *(const float4*)&at[k][64+ty*4];
            float4 b0 = *(const float4*)&bt[k][tx*4];
            float4 b1 = *(const float4*)&bt[k][64+tx*4];
            float av[8] = {a0.x,a0.y,a0.z,a0.w,a1.x,a1.y,a1.z,a1.w};
            float bv[8] = {b0.x,b0.y,b0.z,b0.w,b1.x,b1.y,b1.z,b1.w};
            #pragma unroll
            for (int u=0;u<8;u++){
                #pragma unroll
                for (int v=0;v<8;v++) acc[u][v] += av[u]*bv[v];
            }
        }
    }
    #pragma unroll
    for (int u=0;u<8;u++){
        int rr = r0 + ((u<4)? ty*4+u : 64+ty*4+(u-4));
        float4 s0 = {acc[u][0],acc[u][1],acc[u][2],acc[u][3]};
        float4 s1 = {acc[u][4],acc[u][5],acc[u][6],acc[u][7]};
        *(float4*)&scores[(size_t)rr*NN + c0 + tx*4] = s0;
        *(float4*)&scores[(size_t)rr*NN + c0 + 64 + tx*4] = s1;
        float m = acc[u][0];
        #pragma unroll
        for (int v=1;v<8;v++) m = fmaxf(m, acc[u][v]);
        #pragma unroll
        for (int s=1;s<16;s<<=1) m = fmaxf(m, __shfl_xor(m, s, 64));
        if (tx==0) atomicMax(&rowmaxenc[rr], enc_f(m));
    }
}

// ---------- phase 6: fused A/oushi/convs + M@Ot partials + minmax ----------
__global__ __launch_bounds__(256) void k_mcat(const float* __restrict__ scores,
        const unsigned* __restrict__ rowmaxenc, const float* __restrict__ maxd,
        const float* __restrict__ dx1, const float* __restrict__ x0,
        const float* __restrict__ Wcy3, const float* __restrict__ Wcx3,
        const float* __restrict__ Wcy5, const float* __restrict__ Wcx5,
        const float* __restrict__ Wcy9, const float* __restrict__ Wcx9,
        const float* __restrict__ bcy3, const float* __restrict__ bcx3,
        const float* __restrict__ bcy5, const float* __restrict__ bcx5,
        const float* __restrict__ bcy9, const float* __restrict__ bcx9,
        float* __restrict__ mnmx, float* __restrict__ hpart){
    __shared__ float As[40][76];
    __shared__ float invr[40];
    __shared__ float2 pj[64];
    __shared__ float4 ots[64];
    __shared__ float2 pi[32];
    __shared__ float im[32];
    __shared__ float smn[256], smx[256];
    int xb = blockIdx.x, yb = blockIdx.y;
    int i0 = yb*32, j0 = xb*64;
    int tid = threadIdx.x;
    float wy3[3],wx3[3],wy5[5],wx5[5],wy9[9],wx9[9];
    #pragma unroll
    for (int t=0;t<3;t++){ wy3[t]=Wcy3[t]; wx3[t]=Wcx3[t]; }
    #pragma unroll
    for (int t=0;t<5;t++){ wy5[t]=Wcy5[t]; wx5[t]=Wcx5[t]; }
    #pragma unroll
    for (int t=0;t<9;t++){ wy9[t]=Wcy9[t]; wx9[t]=Wcx9[t]; }
    float bc3 = bcy3[0]+bcx3[0];
    float bc5 = bcy5[0]+bcx5[0];
    float bc9 = bcy9[0]+bcx9[0];
    if (tid < 40){
        int gr = i0-4+tid;
        invr[tid] = ((unsigned)gr < NN) ? 1.f/dec_f(rowmaxenc[gr]) : 0.f;
    } else if (tid >= 64 && tid < 128){
        int c = tid-64, j = j0+c;
        float4 v = *(const float4*)&dx1[j*4];
        pj[c] = make_float2(v.x, v.y);
        ots[c] = *(const float4*)&x0[j*8+4];
    } else if (tid >= 128 && tid < 160){
        int r = tid-128;
        float4 v = *(const float4*)&dx1[(i0+r)*4];
        pi[r] = make_float2(v.x, v.y);
        im[r] = 1.f/maxd[i0+r];
    }
    __syncthreads();
    for (int idx=tid; idx<40*72; idx+=256){
        int lr = idx/72, lc = idx - lr*72;
        int gr = i0-4+lr, gc = j0-4+lc;
        float v = 0.f;
        if ((unsigned)gr < NN && (unsigned)gc < NN)
            v = scores[(size_t)gr*NN + gc]*invr[lr];
        As[lr][lc] = v;
    }
    __syncthreads();
    int r = tid>>3, cb = tid&7, c0l = cb*8;
    float acc9[8]={0,0,0,0,0,0,0,0}, acc5[8]={0,0,0,0,0,0,0,0}, acc3[8]={0,0,0,0,0,0,0,0}, ctr[8];
    #pragma unroll
    for (int u=0;u<9;u++){
        float4 a = *(const float4*)&As[r+u][c0l+4];
        float4 b = *(const float4*)&As[r+u][c0l+8];
        float vals[8] = {a.x,a.y,a.z,a.w,b.x,b.y,b.z,b.w};
        #pragma unroll
        for (int q=0;q<8;q++){
            acc9[q] += vals[q]*wx9[u];
            if (u>=2 && u<=6) acc5[q] += vals[q]*wx5[u-2];
            if (u>=3 && u<=5) acc3[q] += vals[q]*wx3[u-3];
            if (u==4) ctr[q] = vals[q];
        }
    }
    float win[16];
    #pragma unroll
    for (int q4=0;q4<4;q4++){
        float4 w4 = *(const float4*)&As[r+4][c0l+q4*4];
        win[q4*4+0]=w4.x; win[q4*4+1]=w4.y; win[q4*4+2]=w4.z; win[q4*4+3]=w4.w;
    }
    float mn = INFINITY, mx = -INFINITY;
    float pd0=0,pd1=0,pd2=0,pd3=0;
    float2 ppi = pi[r];
    float imv = im[r];
    #pragma unroll
    for (int q=0;q<8;q++){
        float cy9=0.f;
        #pragma unroll
        for (int u=0;u<9;u++) cy9 += win[q+u]*wy9[u];
        float cy5=0.f;
        #pragma unroll
        for (int u=0;u<5;u++) cy5 += win[q+2+u]*wy5[u];
        float cy3=0.f;
        #pragma unroll
        for (int u=0;u<3;u++) cy3 += win[q+3+u]*wy3[u];
        float c3v = cy3+acc3[q]+bc3;
        float c5v = cy5+acc5[q]+bc5;
        float c9v = cy9+acc9[q]+bc9;
        float a = ctr[q];
        float2 pjv = pj[c0l+q];
        float dxp = ppi.x-pjv.x, dyp = ppi.y-pjv.y;
        float ou = 1.f - sqrtf(dxp*dxp+dyp*dyp)*imv;
        float Mv = a + ou + c3v + c5v + c9v;
        mn = fminf(mn, fminf(fminf(a,ou), fminf(fminf(c3v,c5v),c9v)));
        mx = fmaxf(mx, fmaxf(fmaxf(a,ou), fmaxf(fmaxf(c3v,c5v),c9v)));
        float4 ot = ots[c0l+q];
        pd0 += Mv*ot.x; pd1 += Mv*ot.y; pd2 += Mv*ot.z; pd3 += Mv*ot.w;
    }
    #pragma unroll
    for (int m=1;m<8;m<<=1){
        pd0 += __shfl_xor(pd0, m, 64);
        pd1 += __shfl_xor(pd1, m, 64);
        pd2 += __shfl_xor(pd2, m, 64);
        pd3 += __shfl_xor(pd3, m, 64);
    }
    if (cb==0){
        float4 pd = {pd0,pd1,pd2,pd3};
        *(float4*)&hpart[((size_t)(i0+r)*64 + xb)*4] = pd;
    }
    smn[tid]=mn; smx[tid]=mx; __syncthreads();
    for (int s=128;s>0;s>>=1){
        if (tid<s){ smn[tid]=fminf(smn[tid],smn[tid+s]); smx[tid]=fmaxf(smx[tid],smx[tid+s]); }
        __syncthreads();
    }
    if (tid==0){
        int bid = yb*64 + xb;
        mnmx[bid] = smn[0];
        mnmx[8192 + bid] = smx[0];
    }
}

// ---------- phase 6b: reduce per-block minmax ----------
__global__ __launch_bounds__(256) void k_gmm(const float* __restrict__ mnmx, float* __restrict__ gmm){
    __shared__ float smn[256], smx[256];
    int tid = threadIdx.x;
    float mn = INFINITY, mx = -INFINITY;
    for (int i=tid; i<8192; i+=256){
        mn = fminf(mn, mnmx[i]);
        mx = fmaxf(mx, mnmx[8192+i]);
    }
    smn[tid]=mn; smx[tid]=mx; __syncthreads();
    for (int s=128;s>0;s>>=1){
        if (tid<s){ smn[tid]=fminf(smn[tid],smn[tid+s]); smx[tid]=fmaxf(smx[tid],smx[tid+s]); }
        __syncthreads();
    }
    if (tid==0){ gmm[0]=smn[0]; gmm[1]=smx[0]; }
}

// ---------- phase 7a: reduce partials + affine ----------
__global__ __launch_bounds__(256) void k_hred(const float* __restrict__ hpart,
        const float* __restrict__ gmm, const float* __restrict__ colsum,
        float* __restrict__ hfin){
    int i = blockIdx.x*256 + threadIdx.x;
    if (i >= NN) return;
    float4 sum = {0,0,0,0};
    const float4* hp = (const float4*)hpart + (size_t)i*64;
    for (int xb=0; xb<64; xb++){
        float4 v = hp[xb];
        sum.x+=v.x; sum.y+=v.y; sum.z+=v.z; sum.w+=v.w;
    }
    float mnv = gmm[0], mxv = gmm[1];
    float s = 1.f/(mxv-mnv), o = -mnv*s;
    float4 cs = *(const float4*)colsum;
    float4 out;
    out.x = s*sum.x + 5.f*o*cs.x;
    out.y = s*sum.y + 5.f*o*cs.y;
    out.z = s*sum.z + 5.f*o*cs.z;
    out.w = s*sum.w + 5.f*o*cs.w;
    *(float4*)&hfin[i*4] = out;
}

// ---------- phase 7b: MLP head ----------
__global__ __launch_bounds__(256) void k_mlp(const float* __restrict__ hfin,
        const float* __restrict__ Woff, const float* __restrict__ boff, const float* __restrict__ pw,
        const float* __restrict__ Wf1, const float* __restrict__ bf1,
        const float* __restrict__ Wf2, const float* __restrict__ bf2,
        const float* __restrict__ Wf3, const float* __restrict__ bf3,
        float* __restrict__ out){
    __shared__ float h1[8][128];
    __shared__ float h2[8][256];
    __shared__ float h3[8][256];
    __shared__ float4 red4[256];
    int n0 = blockIdx.x*8, tid = threadIdx.x;
    float p = pw[0];
    {
        int c = tid & 127, mb = (tid>>7)*4;
        #pragma unroll
        for (int mm=0; mm<4; mm++){
            int m = mb+mm;
            float v = boff[c];
            #pragma unroll
            for (int k=0;k<4;k++) v += hfin[(n0+m)*4+k]*Woff[k*128+c];
            h1[m][c] = v>0.f ? v : p*v;
        }
    }
    __syncthreads();
    {
        int c = tid;
        float acc[8];
        #pragma unroll
        for (int m=0;m<8;m++) acc[m] = bf1[c];
        for (int k=0;k<128;k++){
            float w = Wf1[k*256+c];
            #pragma unroll
            for (int m=0;m<8;m++) acc[m] += h1[m][k]*w;
        }
        #pragma unroll
        for (int m=0;m<8;m++) h2[m][c] = acc[m]>0.f?acc[m]:0.f;
    }
    __syncthreads();
    {
        int c = tid;
        float acc[8];
        #pragma unroll
        for (int m=0;m<8;m++) acc[m] = bf2[c];
        for (int k=0;k<256;k++){
            float w = Wf2[k*256+c];
            #pragma unroll
            for (int m=0;m<8;m++) acc[m] += h2[m][k]*w;
        }
        #pragma unroll
        for (int m=0;m<8;m++) h3[m][c] = acc[m]>0.f?acc[m]:0.f;
    }
    __syncthreads();
    float w3_0 = Wf3[tid*4+0], w3_1 = Wf3[tid*4+1], w3_2 = Wf3[tid*4+2], w3_3 = Wf3[tid*4+3];
    for (int m=0;m<8;m++){
        float hv = h3[m][tid];
        float4 r; r.x = hv*w3_0; r.y = hv*w3_1; r.z = hv*w3_2; r.w = hv*w3_3;
        red4[tid]=r; __syncthreads();
        for (int s=128;s>0;s>>=1){
            if(tid<s){
                red4[tid].x+=red4[tid+s].x; red4[tid].y+=red4[tid+s].y;
                red4[tid].z+=red4[tid+s].z; red4[tid].w+=red4[tid+s].w;
            }
            __syncthreads();
        }
        if (tid==0){
            float4 o;
            o.x = red4[0].x + bf3[0]; o.y = red4[0].y + bf3[1];
            o.z = red4[0].z + bf3[2]; o.w = red4[0].w + bf3[3];
            *(float4*)&out[(n0+m)*4] = o;
        }
        __syncthreads();
    }
}

// ---------- host ----------
extern "C" void kernel_launch(void* const* d_in, const int* in_sizes, int n_in,
                              void* d_out, int out_size, void* d_ws, size_t ws_size,
                              hipStream_t stream){
    const float* dx1  = (const float*)d_in[0];
    const float* dx2  = (const float*)d_in[1];
    const float* Wk   = (const float*)d_in[2];
    const float* bk   = (const float*)d_in[3];
    const float* Wg1  = (const float*)d_in[4];
    const float* bg1  = (const float*)d_in[5];
    const float* Wg2  = (const float*)d_in[6];
    const float* bg2  = (const float*)d_in[7];
    const float* Wq   = (const float*)d_in[8];
    const float* bq   = (const float*)d_in[9];
    const float* Wkey = (const float*)d_in[10];
    const float* bkey = (const float*)d_in[11];
    const float* Woff = (const float*)d_in[12];
    const float* boff = (const float*)d_in[13];
    const float* pw   = (const float*)d_in[14];
    const float* Wf1  = (const float*)d_in[15];
    const float* bf1  = (const float*)d_in[16];
    const float* Wf2  = (const float*)d_in[17];
    const float* bf2  = (const float*)d_in[18];
    const float* Wf3  = (const float*)d_in[19];
    const float* bf3  = (const float*)d_in[20];
    const float* Wcy3 = (const float*)d_in[21];
    const float* bcy3 = (const float*)d_in[22];
    const float* Wcx3 = (const float*)d_in[23];
    const float* bcx3 = (const float*)d_in[24];
    const float* Wcy5 = (const float*)d_in[25];
    const float* bcy5 = (const float*)d_in[26];
    const float* Wcx5 = (const float*)d_in[27];
    const float* bcx5 = (const float*)d_in[28];
    const float* Wcy9 = (const float*)d_in[29];
    const float* bcy9 = (const float*)d_in[30];
    const float* Wcx9 = (const float*)d_in[31];
    const float* bcx9 = (const float*)d_in[32];

    char* ws = (char*)d_ws;
    size_t off = 0;
    auto alloc = [&](size_t b)->void*{ void* p = ws + off; off += (b + 255) & ~(size_t)255; return p; };

    // --- zero-init region (one small memset) ---
    char* zbase = ws + off;
    float*    colsum    = (float*)   alloc(4*4);
    int*      cnt3      = (int*)     alloc((size_t)NN*4);
    int*      cnt5      = (int*)     alloc((size_t)NN*4);
    int*      cnt9      = (int*)     alloc((size_t)NN*4);
    int*      cur       = (int*)     alloc((size_t)3*NN*4);
    unsigned* rowmaxenc = (unsigned*)alloc((size_t)NN*4);
    size_t zbytes = (size_t)((ws + off) - zbase);

    // --- non-zeroed ---
    float* x0     = (float*)alloc((size_t)NN*8*4);
    float* maxd   = (float*)alloc((size_t)NN*4);
    int*   nbr    = (int*)  alloc((size_t)NN*9*4);
    int*   offc   = (int*)  alloc((size_t)3*NN*4);
    float* dinvc  = (float*)alloc((size_t)3*NN*4);
    int*   rev    = (int*)  alloc((size_t)NN*17*4);
    float* xw     = (float*)alloc((size_t)NN*64*4);
    float* y2     = (float*)alloc((size_t)3*NN*128*4);
    float* emb    = (float*)alloc((size_t)NN*384*4);
    float* qb     = (float*)alloc((size_t)NN*128*4);
    float* kb     = (float*)alloc((size_t)NN*128*4);
    float* scores = (float*)alloc((size_t)NN*NN*4);
    float* mnmx   = (float*)alloc((size_t)2*8192*4);
    float* hpart  = (float*)alloc((size_t)NN*64*4*4);
    float* gmm    = (float*)alloc(2*4);
    float* hfin   = (float*)alloc((size_t)NN*4*4);
    (void)ws_size; (void)in_sizes; (void)n_in; (void)out_size;

    hipMemsetAsync(zbase, 0, zbytes, stream);

    k_prep<<<16,256,0,stream>>>(dx1,dx2,Wk,bk,x0,colsum);
    k_dist<<<NN/4,256,0,stream>>>(dx1,maxd,nbr,cnt3,cnt5,cnt9);
    k_scan<<<1,256,0,stream>>>(cnt3,cnt5,cnt9,offc,dinvc);
    k_fill<<<16,256,0,stream>>>(nbr,offc,cur,rev);

    k_y1  <<<NN*64/256,256,0,stream>>>(x0,Wg1,xw);
    k_h1y2<<<NN/4,256,0,stream>>>(xw,offc,cnt3,cnt5,cnt9,rev,dinvc,bg1,Wg2,y2);
    k_fin <<<NN*3,128,0,stream>>>(y2,offc,cnt3,cnt5,cnt9,rev,dinvc,bg2,emb);

    k_qk<<<NN/8,256,0,stream>>>(emb,Wq,bq,Wkey,bkey,qb,kb);
    k_scores<<<1024,256,0,stream>>>(qb,kb,scores,rowmaxenc);
    k_mcat<<<dim3(64,128),256,0,stream>>>(scores,rowmaxenc,maxd,dx1,x0,
        Wcy3,Wcx3,Wcy5,Wcx5,Wcy9,Wcx9,
        bcy3,bcx3,bcy5,bcx5,bcy9,bcx9, mnmx, hpart);
    k_gmm<<<1,256,0,stream>>>(mnmx,gmm);
    k_hred<<<NN/256,256,0,stream>>>(hpart,gmm,colsum,hfin);
    k_mlp<<<NN/8,256,0,stream>>>(hfin,Woff,boff,pw,Wf1,bf1,Wf2,bf2,Wf3,bf3,(float*)d_out);
}

// Round 5
// 335.011 us; speedup vs baseline: 1.8163x; 1.0587x over previous
//
#include <hip/hip_runtime.h>
#include <math.h>

#define NN 4096

static __device__ __forceinline__ unsigned enc_f(float f){
    unsigned u = __float_as_uint(f);
    return (u & 0x80000000u) ? ~u : (u | 0x80000000u);
}
static __device__ __forceinline__ float dec_f(unsigned u){
    unsigned b = (u & 0x80000000u) ? (u & 0x7fffffffu) : ~u;
    return __uint_as_float(b);
}

// ---------- phase 1: x0 assembly + Ot column sums ----------
__global__ void k_prep(const float* __restrict__ dx1, const float* __restrict__ dx2,
                       const float* __restrict__ Wk, const float* __restrict__ bk,
                       float* __restrict__ x0, float* __restrict__ colsum){
    int n = blockIdx.x*blockDim.x + threadIdx.x;
    if (n >= NN) return;
    float wk[8];
    #pragma unroll
    for (int j=0;j<8;j++) wk[j] = Wk[j];
    float bkv = bk[0];
    #pragma unroll
    for (int c=0;c<4;c++) x0[n*8+c] = dx1[n*4+c];
    #pragma unroll
    for (int c=0;c<4;c++){
        float acc = bkv;
        #pragma unroll
        for (int j=0;j<8;j++) acc += dx2[(n*8+j)*4+c]*wk[j];
        x0[n*8+4+c] = acc;
        atomicAdd(&colsum[c], acc);
    }
}

// ---------- phase 2: row max dist + top-9 knn + int in-degree counts ----------
__global__ __launch_bounds__(256) void k_dist(const float* __restrict__ dx1,
        float* __restrict__ maxd, int* __restrict__ nbr,
        int* __restrict__ cnt3, int* __restrict__ cnt5, int* __restrict__ cnt9){
    __shared__ float2 ps[NN];
    int tid = threadIdx.x;
    for (int j=tid; j<NN; j+=256){
        float4 v = *(const float4*)&dx1[j*4];
        ps[j] = make_float2(v.x, v.y);
    }
    __syncthreads();
    int lane = tid & 63;
    int i = blockIdx.x*4 + (tid>>6);
    float2 pi = ps[i];
    unsigned long long best[9];
    #pragma unroll
    for (int q=0;q<9;q++) best[q] = ~0ULL;
    float lmax = 0.f;
    for (int t=0;t<64;t++){
        int j = (t<<6) | lane;
        float2 p = ps[j];
        float dx = pi.x - p.x, dy = pi.y - p.y;
        float d = sqrtf(dx*dx + dy*dy);
        lmax = fmaxf(lmax, d);
        unsigned long long cand = ((unsigned long long)__float_as_uint(d) << 32) | (unsigned)j;
        if (j != i && cand < best[8]){
            best[8] = cand;
            #pragma unroll
            for (int q=8; q>0; --q){
                if (best[q] < best[q-1]){ unsigned long long tm=best[q]; best[q]=best[q-1]; best[q-1]=tm; }
            }
        }
    }
    #pragma unroll
    for (int m=1;m<64;m<<=1) lmax = fmaxf(lmax, __shfl_xor(lmax, m, 64));
    if (lane==0) maxd[i] = lmax;
    for (int t=0;t<9;t++){
        unsigned long long w = best[0];
        #pragma unroll
        for (int m=1;m<64;m<<=1){
            unsigned long long o = __shfl_xor(w, m, 64);
            if (o < w) w = o;
        }
        if (best[0] == w){
            #pragma unroll
            for (int q=0;q<8;q++) best[q] = best[q+1];
            best[8] = ~0ULL;
        }
        if (lane==0){
            int j = (int)(w & 0xffffffffu);
            nbr[i*9+t] = j;
            atomicAdd(&cnt9[j], 1);
            if (t<5) atomicAdd(&cnt5[j], 1);
            if (t<3) atomicAdd(&cnt3[j], 1);
        }
    }
}

// ---------- phase 2b: CSR offsets (exclusive scan) + dinv ----------
__global__ __launch_bounds__(256) void k_scan(const int* __restrict__ cnt3,
        const int* __restrict__ cnt5, const int* __restrict__ cnt9,
        int* __restrict__ offc, float* __restrict__ dinvc){
    __shared__ int part[256];
    int tid = threadIdx.x;
    for (int g=0; g<3; g++){
        const int* cp = g==0?cnt3:(g==1?cnt5:cnt9);
        int base = tid*16;
        int loc[16]; int s=0;
        #pragma unroll
        for (int q=0;q<16;q++){ loc[q]=s; s += cp[base+q]; }
        part[tid]=s; __syncthreads();
        for (int d=1; d<256; d<<=1){
            int v = (tid>=d) ? part[tid-d] : 0;
            __syncthreads();
            part[tid] += v;
            __syncthreads();
        }
        int pre = (tid==0) ? 0 : part[tid-1];
        #pragma unroll
        for (int q=0;q<16;q++){
            offc[g*NN + base + q]  = pre + loc[q];
            dinvc[g*NN + base + q] = rsqrtf((float)cp[base+q] + 1.f);
        }
        __syncthreads();
    }
}

// ---------- phase 2c: fill reverse-edge lists ----------
__global__ void k_fill(const int* __restrict__ nbr, const int* __restrict__ offc,
        int* __restrict__ cur, int* __restrict__ rev){
    int i = blockIdx.x*256 + threadIdx.x;
    if (i >= NN) return;
    #pragma unroll
    for (int t=0;t<9;t++){
        int j = nbr[i*9+t];
        int gmin = t<3 ? 0 : (t<5 ? 1 : 2);
        for (int g=gmin; g<3; g++){
            int pos = atomicAdd(&cur[g*NN+j], 1);
            int rb = (g==0) ? 0 : (g==1 ? NN*3 : NN*8);
            rev[rb + offc[g*NN+j] + pos] = i;
        }
    }
}

// ---------- phase 3: GCN layer-1 input transform (shared across graphs) ----------
__global__ void k_y1(const float* __restrict__ x0, const float* __restrict__ Wg1,
                     float* __restrict__ xw){
    int idx = blockIdx.x*256 + threadIdx.x;
    if (idx >= NN*64) return;
    int n = idx>>6, c = idx&63;
    float acc = 0.f;
    #pragma unroll
    for (int k=0;k<8;k++) acc += x0[n*8+k]*Wg1[k*64+c];
    xw[idx] = acc;
}

// ---------- phase 3b: gather layer-1 + relu + layer-2 matmul ----------
__global__ __launch_bounds__(256) void k_h1y2(const float* __restrict__ xw,
        const int* __restrict__ offc,
        const int* __restrict__ cnt3, const int* __restrict__ cnt5, const int* __restrict__ cnt9,
        const int* __restrict__ rev, const float* __restrict__ dinvc,
        const float* __restrict__ bg1, const float* __restrict__ Wg2,
        float* __restrict__ y2){
    __shared__ float h1s[12][64];
    int n0 = blockIdx.x*4, tid = threadIdx.x;
    for (int s=tid; s<768; s+=256){
        int p = s>>6, k = s&63, g = p>>2, n = n0+(p&3);
        const int* cp = g==0?cnt3:(g==1?cnt5:cnt9);
        int rb = (g==0) ? 0 : (g==1 ? NN*3 : NN*8);
        int cnt = cp[n];
        int o = rb + offc[g*NN+n];
        float dv = dinvc[g*NN+n];
        float srow = dv*xw[n*64+k];
        for (int e=0;e<cnt;e++){
            int i = rev[o+e];
            srow += dinvc[g*NN+i]*xw[i*64+k];
        }
        float v = dv*srow + bg1[k];
        h1s[p][k] = v>0.f ? v : 0.f;
    }
    __syncthreads();
    int c = tid & 127, ph = tid>>7;
    float a6[6] = {0,0,0,0,0,0};
    for (int k=0;k<64;k++){
        float w = Wg2[k*128+c];
        #pragma unroll
        for (int q=0;q<6;q++) a6[q] += h1s[q*2+ph][k]*w;
    }
    #pragma unroll
    for (int q=0;q<6;q++){
        int p = q*2+ph, g = p>>2, n = n0+(p&3);
        float dv = dinvc[g*NN+n];
        y2[(size_t)g*NN*128 + (size_t)n*128 + c] = dv*a6[q];
    }
}

// ---------- phase 3c: gather layer-2 + bias + log_softmax ----------
__global__ __launch_bounds__(128) void k_fin(const float* __restrict__ y2,
        const int* __restrict__ offc,
        const int* __restrict__ cnt3, const int* __restrict__ cnt5, const int* __restrict__ cnt9,
        const int* __restrict__ rev, const float* __restrict__ dinvc,
        const float* __restrict__ bg2, float* __restrict__ emb){
    __shared__ float sm[2], ss[2];
    int b = blockIdx.x;
    int n = b & (NN-1), g = b >> 12;
    const int* cp = g==0?cnt3:(g==1?cnt5:cnt9);
    int rb = (g==0) ? 0 : (g==1 ? NN*3 : NN*8);
    int cnt = cp[n];
    int o = rb + offc[g*NN+n];
    float dv = dinvc[g*NN+n];
    int c = threadIdx.x;
    const float* yg = y2 + (size_t)g*NN*128;
    float s = yg[(size_t)n*128 + c];
    for (int e=0;e<cnt;e++){
        int i = rev[o+e];
        s += yg[(size_t)i*128 + c];
    }
    float v = dv*s + bg2[c];
    float m = v;
    #pragma unroll
    for (int st=1;st<64;st<<=1) m = fmaxf(m, __shfl_xor(m, st, 64));
    if ((c&63)==0) sm[c>>6] = m;
    __syncthreads();
    m = fmaxf(sm[0], sm[1]);
    float e = expf(v - m);
    float t = e;
    #pragma unroll
    for (int st=1;st<64;st<<=1) t += __shfl_xor(t, st, 64);
    if ((c&63)==0) ss[c>>6] = t;
    __syncthreads();
    t = ss[0]+ss[1];
    emb[n*384 + g*128 + c] = v - m - logf(t);
}

// ---------- phase 4: q/k projections ----------
__global__ __launch_bounds__(256) void k_qk(const float* __restrict__ emb,
        const float* __restrict__ Wq, const float* __restrict__ bq,
        const float* __restrict__ Wkey, const float* __restrict__ bkey,
        float* __restrict__ q, float* __restrict__ kbuf){
    __shared__ float es[8][384];
    int n0 = blockIdx.x*8;
    int tid = threadIdx.x;
    for (int idx=tid; idx<8*384; idx+=256){
        int m = idx/384, k = idx%384;
        es[m][k] = emb[(n0+m)*384+k];
    }
    __syncthreads();
    int c = tid & 127;
    int sel = tid >> 7;
    const float* W = sel ? Wkey : Wq;
    float b = sel ? bkey[c] : bq[c];
    float acc[8];
    #pragma unroll
    for (int m=0;m<8;m++) acc[m]=b;
    for (int k=0;k<384;k++){
        float w = W[k*128+c];
        #pragma unroll
        for (int m=0;m<8;m++) acc[m] += es[m][k]*w;
    }
    float* out = sel ? kbuf : q;
    #pragma unroll
    for (int m=0;m<8;m++) out[(n0+m)*128+c] = acc[m];
}

// ---------- phase 5: scores = q @ k^T + fused per-row max & min ----------
__global__ __launch_bounds__(256) void k_scores(const float* __restrict__ q,
        const float* __restrict__ kb, float* __restrict__ scores,
        unsigned* __restrict__ rowmaxenc, unsigned* __restrict__ rowminenc){
    __shared__ float at[32][132];
    __shared__ float bt[32][132];
    int bx = blockIdx.x & 31;
    int by = blockIdx.x >> 5;
    int r0 = by*128, c0 = bx*128;
    int tid = threadIdx.x;
    int tx = tid & 15, ty = tid >> 4;
    float acc[8][8] = {};
    for (int k0 = 0; k0 < 128; k0 += 32){
        __syncthreads();
        #pragma unroll
        for (int l=0; l<4; l++){
            int idx = tid + l*256;
            int rowi = idx >> 3;
            int kq  = (idx & 7) * 4;
            float4 a = *(const float4*)&q [(size_t)(r0+rowi)*128 + k0 + kq];
            float4 b = *(const float4*)&kb[(size_t)(c0+rowi)*128 + k0 + kq];
            at[kq+0][rowi]=a.x; at[kq+1][rowi]=a.y; at[kq+2][rowi]=a.z; at[kq+3][rowi]=a.w;
            bt[kq+0][rowi]=b.x; bt[kq+1][rowi]=b.y; bt[kq+2][rowi]=b.z; bt[kq+3][rowi]=b.w;
        }
        __syncthreads();
        #pragma unroll
        for (int k=0;k<32;k++){
            float4 a0 = *(const float4*)&at[k][ty*4];
            float4 a1 = *(const float4*)&at[k][64+ty*4];
            float4 b0 = *(const float4*)&bt[k][tx*4];
            float4 b1 = *(const float4*)&bt[k][64+tx*4];
            float av[8] = {a0.x,a0.y,a0.z,a0.w,a1.x,a1.y,a1.z,a1.w};
            float bv[8] = {b0.x,b0.y,b0.z,b0.w,b1.x,b1.y,b1.z,b1.w};
            #pragma unroll
            for (int u=0;u<8;u++){
                #pragma unroll
                for (int v=0;v<8;v++) acc[u][v] += av[u]*bv[v];
            }
        }
    }
    #pragma unroll
    for (int u=0;u<8;u++){
        int rr = r0 + ((u<4)? ty*4+u : 64+ty*4+(u-4));
        float4 s0 = {acc[u][0],acc[u][1],acc[u][2],acc[u][3]};
        float4 s1 = {acc[u][4],acc[u][5],acc[u][6],acc[u][7]};
        *(float4*)&scores[(size_t)rr*NN + c0 + tx*4] = s0;
        *(float4*)&scores[(size_t)rr*NN + c0 + 64 + tx*4] = s1;
        float m = acc[u][0], mn = acc[u][0];
        #pragma unroll
        for (int v=1;v<8;v++){ m = fmaxf(m, acc[u][v]); mn = fminf(mn, acc[u][v]); }
        #pragma unroll
        for (int s=1;s<16;s<<=1){
            m  = fmaxf(m,  __shfl_xor(m,  s, 64));
            mn = fminf(mn, __shfl_xor(mn, s, 64));
        }
        if (tx==0){
            atomicMax(&rowmaxenc[rr], enc_f(m));
            atomicMin(&rowminenc[rr], enc_f(mn));
        }
    }
}

// ---------- phase 6: fused A/oushi/convs + M@Ot partials + conv minmax ----------
// block = 64x64 output tile; thread = 2 rows x 8 cols (two 4-col halves)
// Wcy* = (1,1,1,K) -> conv along COLUMN (W) axis; Wcx* = (1,1,K,1) -> conv along ROW (H) axis.
__global__ __launch_bounds__(256) void k_mcat(const float* __restrict__ scores,
        const unsigned* __restrict__ rowmaxenc, const float* __restrict__ maxd,
        const float* __restrict__ dx1, const float* __restrict__ x0,
        const float* __restrict__ Wcy3, const float* __restrict__ Wcx3,
        const float* __restrict__ Wcy5, const float* __restrict__ Wcx5,
        const float* __restrict__ Wcy9, const float* __restrict__ Wcx9,
        const float* __restrict__ bcy3, const float* __restrict__ bcx3,
        const float* __restrict__ bcy5, const float* __restrict__ bcx5,
        const float* __restrict__ bcy9, const float* __restrict__ bcx9,
        float* __restrict__ mnmx, float* __restrict__ hpart){
    __shared__ float As[72][96];
    __shared__ float invr_s[72];
    __shared__ float4 ots[64];
    __shared__ float2 pjv[64];
    __shared__ float2 piv[64];
    __shared__ float ims[64];
    __shared__ float smn[4], smx[4];
    int bx = blockIdx.x, by = blockIdx.y;
    int i0 = by*64, j0 = bx*64;
    int tid = threadIdx.x;

    float wy3[3],wx3[3],wy5[5],wx5[5],wy9[9],wx9[9];
    #pragma unroll
    for (int t=0;t<3;t++){ wy3[t]=Wcy3[t]; wx3[t]=Wcx3[t]; }
    #pragma unroll
    for (int t=0;t<5;t++){ wy5[t]=Wcy5[t]; wx5[t]=Wcx5[t]; }
    #pragma unroll
    for (int t=0;t<9;t++){ wy9[t]=Wcy9[t]; wx9[t]=Wcx9[t]; }
    float bc3 = bcy3[0]+bcx3[0];
    float bc5 = bcy5[0]+bcx5[0];
    float bc9 = bcy9[0]+bcx9[0];

    if (tid < 72){
        int gr = i0-4+tid;
        invr_s[tid] = ((unsigned)gr < NN) ? 1.f/dec_f(rowmaxenc[gr]) : 0.f;
    } else if (tid >= 96 && tid < 160){
        int c = tid-96, j = j0+c;
        float4 v = *(const float4*)&dx1[j*4];
        pjv[c] = make_float2(v.x, v.y);
        ots[c] = *(const float4*)&x0[j*8+4];
    } else if (tid >= 160 && tid < 224){
        int r = tid-160;
        float4 v = *(const float4*)&dx1[(i0+r)*4];
        piv[r] = make_float2(v.x, v.y);
        ims[r] = 1.f/maxd[i0+r];
    }
    __syncthreads();

    // stage 72 rows x 20 float4 (global cols j0-8 .. j0+71), row-clamped reads (iv=0 kills OOR)
    bool colEdge = (bx == 0) || (bx == 63);
    for (int s = tid; s < 72*20; s += 256){
        int row = s/20, c4 = s - row*20;
        int gr = i0 - 4 + row;
        int grc = gr < 0 ? 0 : (gr > NN-1 ? NN-1 : gr);
        int gcf = j0 - 8 + c4*4;
        float iv = invr_s[row];
        float4 v;
        if (!colEdge){
            v = *(const float4*)&scores[(size_t)grc*NN + gcf];
        } else {
            v = make_float4(0.f,0.f,0.f,0.f);
            const float* rp = &scores[(size_t)grc*NN];
            if ((unsigned)(gcf+0) < NN) v.x = rp[gcf+0];
            if ((unsigned)(gcf+1) < NN) v.y = rp[gcf+1];
            if ((unsigned)(gcf+2) < NN) v.z = rp[gcf+2];
            if ((unsigned)(gcf+3) < NN) v.w = rp[gcf+3];
        }
        int sc4 = c4 ^ ((row & 3) << 1);
        float* dst = &As[row][sc4*4];
        dst[0]=v.x*iv; dst[1]=v.y*iv; dst[2]=v.z*iv; dst[3]=v.w*iv;
    }
    __syncthreads();

    int rp = tid >> 3, cg = tid & 7;
    int r0l = rp*2;
    float mn = INFINITY, mx = -INFINITY;
    float pdx[2]={0,0}, pdy[2]={0,0}, pdz[2]={0,0}, pdw[2]={0,0};
    float2 prow0 = piv[r0l], prow1 = piv[r0l+1];
    float im0 = ims[r0l], im1 = ims[r0l+1];

    for (int h = 0; h < 2; ++h){
        int cbase = cg*8 + h*4;
        // row-direction window: LDS rows r0l..r0l+9 at fixed float4 col (cbase+8)
        float colw[10][4];
        #pragma unroll
        for (int u=0; u<10; ++u){
            int row = r0l+u;
            int c4 = ((cbase+8)>>2) ^ ((row&3)<<1);
            float4 v = *(const float4*)&As[row][c4*4];
            colw[u][0]=v.x; colw[u][1]=v.y; colw[u][2]=v.z; colw[u][3]=v.w;
        }
        #pragma unroll
        for (int d=0; d<2; ++d){
            int row = r0l+4+d;
            float w[12];
            {
                int c4l = ((cbase+4)>>2) ^ ((row&3)<<1);
                int c4r = ((cbase+12)>>2) ^ ((row&3)<<1);
                float4 l = *(const float4*)&As[row][c4l*4];
                float4 rgt = *(const float4*)&As[row][c4r*4];
                w[0]=l.x; w[1]=l.y; w[2]=l.z; w[3]=l.w;
                #pragma unroll
                for (int k=0;k<4;++k) w[4+k] = colw[4+d][k];
                w[8]=rgt.x; w[9]=rgt.y; w[10]=rgt.z; w[11]=rgt.w;
            }
            float2 prow = d ? prow1 : prow0;
            float imv = d ? im1 : im0;
            #pragma unroll
            for (int c=0;c<4;++c){
                // ROW-axis (H) convs use Wcx*
                float cx9 = 0.f, cx5 = 0.f, cx3 = 0.f;
                #pragma unroll
                for (int u=0;u<9;++u) cx9 += colw[u+d][c]*wx9[u];
                #pragma unroll
                for (int u=0;u<5;++u) cx5 += colw[u+2+d][c]*wx5[u];
                #pragma unroll
                for (int u=0;u<3;++u) cx3 += colw[u+3+d][c]*wx3[u];
                // COLUMN-axis (W) convs use Wcy*
                float cy9 = bc9, cy5 = bc5, cy3 = bc3;
                #pragma unroll
                for (int u=0;u<9;++u) cy9 += w[c+u]*wy9[u];
                #pragma unroll
                for (int u=0;u<5;++u) cy5 += w[c+2+u]*wy5[u];
                #pragma unroll
                for (int u=0;u<3;++u) cy3 += w[c+3+u]*wy3[u];
                float c3v = cy3+cx3, c5v = cy5+cx5, c9v = cy9+cx9;
                mn = fminf(mn, fminf(fminf(c3v,c5v),c9v));
                mx = fmaxf(mx, fmaxf(fmaxf(c3v,c5v),c9v));
                float a = colw[4+d][c];
                float2 pj2 = pjv[cbase+c];
                float ddx = prow.x - pj2.x, ddy = prow.y - pj2.y;
                float ou = 1.f - sqrtf(ddx*ddx + ddy*ddy)*imv;
                float Mv = a + ou + c3v + c5v + c9v;
                float4 ot = ots[cbase+c];
                if (d==0){ pdx[0]+=Mv*ot.x; pdy[0]+=Mv*ot.y; pdz[0]+=Mv*ot.z; pdw[0]+=Mv*ot.w; }
                else     { pdx[1]+=Mv*ot.x; pdy[1]+=Mv*ot.y; pdz[1]+=Mv*ot.z; pdw[1]+=Mv*ot.w; }
            }
        }
    }
    #pragma unroll
    for (int m=1; m<8; m<<=1){
        #pragma unroll
        for (int d=0; d<2; ++d){
            pdx[d] += __shfl_xor(pdx[d], m, 64);
            pdy[d] += __shfl_xor(pdy[d], m, 64);
            pdz[d] += __shfl_xor(pdz[d], m, 64);
            pdw[d] += __shfl_xor(pdw[d], m, 64);
        }
    }
    if (cg == 0){
        #pragma unroll
        for (int d=0; d<2; ++d){
            float4 pd = {pdx[d], pdy[d], pdz[d], pdw[d]};
            *(float4*)&hpart[((size_t)(i0 + r0l + d)*64 + bx)*4] = pd;
        }
    }
    #pragma unroll
    for (int m=1; m<64; m<<=1){
        mn = fminf(mn, __shfl_xor(mn, m, 64));
        mx = fmaxf(mx, __shfl_xor(mx, m, 64));
    }
    int wid = tid >> 6;
    if ((tid & 63) == 0){ smn[wid] = mn; smx[wid] = mx; }
    __syncthreads();
    if (tid == 0){
        float a0 = fminf(fminf(smn[0],smn[1]), fminf(smn[2],smn[3]));
        float b0 = fmaxf(fmaxf(smx[0],smx[1]), fmaxf(smx[2],smx[3]));
        int bid = by*64 + bx;
        mnmx[bid] = a0;
        mnmx[4096 + bid] = b0;
    }
}

// ---------- phase 6b: global min/max = conv blocks ∪ A-range ∪ {0,1} ----------
__global__ __launch_bounds__(256) void k_gmm(const float* __restrict__ mnmx,
        const unsigned* __restrict__ rowminenc, const unsigned* __restrict__ rowmaxenc,
        float* __restrict__ gmm){
    __shared__ float smn[256], smx[256];
    int tid = threadIdx.x;
    float mn = 0.f, mx = 1.f;   // oushi range is exactly [0,1]
    for (int i=tid; i<4096; i+=256){
        mn = fminf(mn, mnmx[i]);
        mx = fmaxf(mx, mnmx[4096+i]);
        float rmx = dec_f(rowmaxenc[i]);
        float q = dec_f(rowminenc[i]) / rmx;
        mn = fminf(mn, fminf(1.f, q));
        mx = fmaxf(mx, fmaxf(1.f, q));
    }
    smn[tid]=mn; smx[tid]=mx; __syncthreads();
    for (int s=128;s>0;s>>=1){
        if (tid<s){ smn[tid]=fminf(smn[tid],smn[tid+s]); smx[tid]=fmaxf(smx[tid],smx[tid+s]); }
        __syncthreads();
    }
    if (tid==0){ gmm[0]=smn[0]; gmm[1]=smx[0]; }
}

// ---------- phase 7a: reduce partials + affine ----------
__global__ __launch_bounds__(256) void k_hred(const float* __restrict__ hpart,
        const float* __restrict__ gmm, const float* __restrict__ colsum,
        float* __restrict__ hfin){
    int i = blockIdx.x*256 + threadIdx.x;
    if (i >= NN) return;
    float4 sum = {0,0,0,0};
    const float4* hp = (const float4*)hpart + (size_t)i*64;
    for (int xb=0; xb<64; xb++){
        float4 v = hp[xb];
        sum.x+=v.x; sum.y+=v.y; sum.z+=v.z; sum.w+=v.w;
    }
    float mnv = gmm[0], mxv = gmm[1];
    float s = 1.f/(mxv-mnv), o = -mnv*s;
    float4 cs = *(const float4*)colsum;
    float4 out;
    out.x = s*sum.x + 5.f*o*cs.x;
    out.y = s*sum.y + 5.f*o*cs.y;
    out.z = s*sum.z + 5.f*o*cs.z;
    out.w = s*sum.w + 5.f*o*cs.w;
    *(float4*)&hfin[i*4] = out;
}

// ---------- phase 7b: MLP head ----------
__global__ __launch_bounds__(256) void k_mlp(const float* __restrict__ hfin,
        const float* __restrict__ Woff, const float* __restrict__ boff, const float* __restrict__ pw,
        const float* __restrict__ Wf1, const float* __restrict__ bf1,
        const float* __restrict__ Wf2, const float* __restrict__ bf2,
        const float* __restrict__ Wf3, const float* __restrict__ bf3,
        float* __restrict__ out){
    __shared__ float h1[8][128];
    __shared__ float h2[8][256];
    __shared__ float h3[8][256];
    __shared__ float4 red4[256];
    int n0 = blockIdx.x*8, tid = threadIdx.x;
    float p = pw[0];
    {
        int c = tid & 127, mb = (tid>>7)*4;
        #pragma unroll
        for (int mm=0; mm<4; mm++){
            int m = mb+mm;
            float v = boff[c];
            #pragma unroll
            for (int k=0;k<4;k++) v += hfin[(n0+m)*4+k]*Woff[k*128+c];
            h1[m][c] = v>0.f ? v : p*v;
        }
    }
    __syncthreads();
    {
        int c = tid;
        float acc[8];
        #pragma unroll
        for (int m=0;m<8;m++) acc[m] = bf1[c];
        for (int k=0;k<128;k++){
            float w = Wf1[k*256+c];
            #pragma unroll
            for (int m=0;m<8;m++) acc[m] += h1[m][k]*w;
        }
        #pragma unroll
        for (int m=0;m<8;m++) h2[m][c] = acc[m]>0.f?acc[m]:0.f;
    }
    __syncthreads();
    {
        int c = tid;
        float acc[8];
        #pragma unroll
        for (int m=0;m<8;m++) acc[m] = bf2[c];
        for (int k=0;k<256;k++){
            float w = Wf2[k*256+c];
            #pragma unroll
            for (int m=0;m<8;m++) acc[m] += h2[m][k]*w;
        }
        #pragma unroll
        for (int m=0;m<8;m++) h3[m][c] = acc[m]>0.f?acc[m]:0.f;
    }
    __syncthreads();
    float w3_0 = Wf3[tid*4+0], w3_1 = Wf3[tid*4+1], w3_2 = Wf3[tid*4+2], w3_3 = Wf3[tid*4+3];
    for (int m=0;m<8;m++){
        float hv = h3[m][tid];
        float4 r; r.x = hv*w3_0; r.y = hv*w3_1; r.z = hv*w3_2; r.w = hv*w3_3;
        red4[tid]=r; __syncthreads();
        for (int s=128;s>0;s>>=1){
            if(tid<s){
                red4[tid].x+=red4[tid+s].x; red4[tid].y+=red4[tid+s].y;
                red4[tid].z+=red4[tid+s].z; red4[tid].w+=red4[tid+s].w;
            }
            __syncthreads();
        }
        if (tid==0){
            float4 o;
            o.x = red4[0].x + bf3[0]; o.y = red4[0].y + bf3[1];
            o.z = red4[0].z + bf3[2]; o.w = red4[0].w + bf3[3];
            *(float4*)&out[(n0+m)*4] = o;
        }
        __syncthreads();
    }
}

// ---------- host ----------
extern "C" void kernel_launch(void* const* d_in, const int* in_sizes, int n_in,
                              void* d_out, int out_size, void* d_ws, size_t ws_size,
                              hipStream_t stream){
    const float* dx1  = (const float*)d_in[0];
    const float* dx2  = (const float*)d_in[1];
    const float* Wk   = (const float*)d_in[2];
    const float* bk   = (const float*)d_in[3];
    const float* Wg1  = (const float*)d_in[4];
    const float* bg1  = (const float*)d_in[5];
    const float* Wg2  = (const float*)d_in[6];
    const float* bg2  = (const float*)d_in[7];
    const float* Wq   = (const float*)d_in[8];
    const float* bq   = (const float*)d_in[9];
    const float* Wkey = (const float*)d_in[10];
    const float* bkey = (const float*)d_in[11];
    const float* Woff = (const float*)d_in[12];
    const float* boff = (const float*)d_in[13];
    const float* pw   = (const float*)d_in[14];
    const float* Wf1  = (const float*)d_in[15];
    const float* bf1  = (const float*)d_in[16];
    const float* Wf2  = (const float*)d_in[17];
    const float* bf2  = (const float*)d_in[18];
    const float* Wf3  = (const float*)d_in[19];
    const float* bf3  = (const float*)d_in[20];
    const float* Wcy3 = (const float*)d_in[21];
    const float* bcy3 = (const float*)d_in[22];
    const float* Wcx3 = (const float*)d_in[23];
    const float* bcx3 = (const float*)d_in[24];
    const float* Wcy5 = (const float*)d_in[25];
    const float* bcy5 = (const float*)d_in[26];
    const float* Wcx5 = (const float*)d_in[27];
    const float* bcx5 = (const float*)d_in[28];
    const float* Wcy9 = (const float*)d_in[29];
    const float* bcy9 = (const float*)d_in[30];
    const float* Wcx9 = (const float*)d_in[31];
    const float* bcx9 = (const float*)d_in[32];

    char* ws = (char*)d_ws;
    size_t off = 0;
    auto alloc = [&](size_t b)->void*{ void* p = ws + off; off += (b + 255) & ~(size_t)255; return p; };

    // --- zero-init region (one small memset) ---
    char* zbase = ws + off;
    float*    colsum    = (float*)   alloc(4*4);
    int*      cnt3      = (int*)     alloc((size_t)NN*4);
    int*      cnt5      = (int*)     alloc((size_t)NN*4);
    int*      cnt9      = (int*)     alloc((size_t)NN*4);
    int*      cur       = (int*)     alloc((size_t)3*NN*4);
    unsigned* rowmaxenc = (unsigned*)alloc((size_t)NN*4);
    size_t zbytes = (size_t)((ws + off) - zbase);
    unsigned* rowminenc = (unsigned*)alloc((size_t)NN*4);   // memset 0xFF

    // --- non-zeroed ---
    float* x0     = (float*)alloc((size_t)NN*8*4);
    float* maxd   = (float*)alloc((size_t)NN*4);
    int*   nbr    = (int*)  alloc((size_t)NN*9*4);
    int*   offc   = (int*)  alloc((size_t)3*NN*4);
    float* dinvc  = (float*)alloc((size_t)3*NN*4);
    int*   rev    = (int*)  alloc((size_t)NN*17*4);
    float* xw     = (float*)alloc((size_t)NN*64*4);
    float* y2     = (float*)alloc((size_t)3*NN*128*4);
    float* emb    = (float*)alloc((size_t)NN*384*4);
    float* qb     = (float*)alloc((size_t)NN*128*4);
    float* kb     = (float*)alloc((size_t)NN*128*4);
    float* scores = (float*)alloc((size_t)NN*NN*4);
    float* mnmx   = (float*)alloc((size_t)2*4096*4);
    float* hpart  = (float*)alloc((size_t)NN*64*4*4);
    float* gmm    = (float*)alloc(2*4);
    float* hfin   = (float*)alloc((size_t)NN*4*4);
    (void)ws_size; (void)in_sizes; (void)n_in; (void)out_size;

    hipMemsetAsync(zbase, 0, zbytes, stream);
    hipMemsetAsync(rowminenc, 0xFF, (size_t)NN*4, stream);

    k_prep<<<16,256,0,stream>>>(dx1,dx2,Wk,bk,x0,colsum);
    k_dist<<<NN/4,256,0,stream>>>(dx1,maxd,nbr,cnt3,cnt5,cnt9);
    k_scan<<<1,256,0,stream>>>(cnt3,cnt5,cnt9,offc,dinvc);
    k_fill<<<16,256,0,stream>>>(nbr,offc,cur,rev);

    k_y1  <<<NN*64/256,256,0,stream>>>(x0,Wg1,xw);
    k_h1y2<<<NN/4,256,0,stream>>>(xw,offc,cnt3,cnt5,cnt9,rev,dinvc,bg1,Wg2,y2);
    k_fin <<<NN*3,128,0,stream>>>(y2,offc,cnt3,cnt5,cnt9,rev,dinvc,bg2,emb);

    k_qk<<<NN/8,256,0,stream>>>(emb,Wq,bq,Wkey,bkey,qb,kb);
    k_scores<<<1024,256,0,stream>>>(qb,kb,scores,rowmaxenc,rowminenc);
    k_mcat<<<dim3(64,64),256,0,stream>>>(scores,rowmaxenc,maxd,dx1,x0,
        Wcy3,Wcx3,Wcy5,Wcx5,Wcy9,Wcx9,
        bcy3,bcx3,bcy5,bcx5,bcy9,bcx9, mnmx, hpart);
    k_gmm<<<1,256,0,stream>>>(mnmx,rowminenc,rowmaxenc,gmm);
    k_hred<<<NN/256,256,0,stream>>>(hpart,gmm,colsum,hfin);
    k_mlp<<<NN/8,256,0,stream>>>(hfin,Woff,boff,pw,Wf1,bf1,Wf2,bf2,Wf3,bf3,(float*)d_out);
}